// Round 3
// baseline (554.659 us; speedup 1.0000x reference)
//
#include <hip/hip_runtime.h>

#define ROI 268
#define NG 512
#define NNODES (NG * ROI)   // 137216
#define CH 32
#define SLOPE 0.33f
#define BN_EPS 1e-5f
#define SR 34               // k_gin LDS row stride (words)
#define RPS (ROI + 1)       // row_ptr per-graph stride

__device__ __forceinline__ float leakyf(float v) {
    return v > 0.f ? v : SLOPE * v;
}

// ---------------------------------------------------------------------------
// K1: y0[N,32] = x[N,268] @ W1_0[268,32]  (fp32 vector GEMM)
// v3 structure (round 3): one thread per output ROW, acc[32] in VGPRs.
//  - No LDS, no barriers, no transpose. Round-2 PMC showed the 2-phase
//    staged structure latency-bound at 2 blocks/CU: VALU 17%, HBM 16%,
//    occupancy 14.5% -- all pipes idle, serialized on stage->sync->compute.
//  - x: per-lane float4 at xr[k4]; the 64B line serves 4 consecutive k4
//    iterations via L1 (256 lanes x 64B = 16KB live, fits 32KB L1).
//  - W: thread-uniform index -> scalar loads (K$/SGPR broadcast), FMA takes
//    the SGPR operand directly. Zero LDS.
//  - VALU floor 15us; memory floor ~26us (cold x). Target ~25us.
// ---------------------------------------------------------------------------
__global__ __launch_bounds__(256) void k_gemm1(
    const float* __restrict__ x, const float* __restrict__ W1,
    float* __restrict__ y0) {
    const size_t row = (size_t)blockIdx.x * 256 + threadIdx.x;
    const float* __restrict__ xr = x + row * ROI;

    float acc[CH];
#pragma unroll
    for (int c = 0; c < CH; c++) acc[c] = 0.f;

    // ROI = 268 = 67 * 4 exactly
#pragma unroll 2
    for (int k4 = 0; k4 < ROI; k4 += 4) {
        float4 a = *(const float4*)&xr[k4];
        float av[4] = {a.x, a.y, a.z, a.w};
#pragma unroll
        for (int j = 0; j < 4; j++) {
            const float* __restrict__ wr = &W1[(k4 + j) * CH];
            const float aj = av[j];
#pragma unroll
            for (int c = 0; c < CH; c++) acc[c] += aj * wr[c];
        }
    }

    float* __restrict__ yr = y0 + row * CH;
#pragma unroll
    for (int c = 0; c < CH; c += 4)
        *(float4*)&yr[c] = make_float4(acc[c], acc[c + 1], acc[c + 2], acc[c + 3]);
}

// ---------------------------------------------------------------------------
// K2: CSR build (by dst node): deg -> per-graph scan + atomic base ticket ->
// fill. row_ptr layout [NG][ROI+1] so per-graph bases are order-free.
// ---------------------------------------------------------------------------
__global__ void k_deg(const int* __restrict__ dst, int E, int* __restrict__ deg) {
    int stride = gridDim.x * blockDim.x;
    for (int i = blockIdx.x * blockDim.x + threadIdx.x; i < E; i += stride)
        atomicAdd(&deg[dst[i]], 1);
}

__global__ __launch_bounds__(512) void k_scan_local(
    int* __restrict__ deg, int* __restrict__ ticket, int* __restrict__ row_ptr) {
    __shared__ int s[512];
    __shared__ int sbase;
    const int g = blockIdx.x, t = threadIdx.x;
    int v = (t < ROI) ? deg[g * ROI + t] : 0;
    s[t] = v;
    __syncthreads();
    for (int d = 1; d < 512; d <<= 1) {
        int u = (t >= d) ? s[t - d] : 0;
        __syncthreads();
        s[t] += u;
        __syncthreads();
    }
    if (t == 511) sbase = atomicAdd(ticket, s[511]);
    __syncthreads();
    const int base = sbase;
    if (t < ROI) {
        int exc = base + s[t] - v;
        row_ptr[g * RPS + t] = exc;
        deg[g * ROI + t] = exc;   // becomes fill cursor
    }
    if (t == 511) row_ptr[g * RPS + ROI] = base + s[511];
}

__global__ void k_fill(const int* __restrict__ src, const int* __restrict__ dst,
                       int E, int* __restrict__ rcur, int* __restrict__ ebuf) {
    int stride = gridDim.x * blockDim.x;
    for (int i = blockIdx.x * blockDim.x + threadIdx.x; i < E; i += stride) {
        int d = dst[i];
        int g = d / ROI;
        int pos = atomicAdd(&rcur[d], 1);
        ebuf[pos] = (src[i] - g * ROI) * SR;   // premultiplied LDS word offset
    }
}

// ---------------------------------------------------------------------------
// K3 helpers
// ---------------------------------------------------------------------------
__device__ __forceinline__ void gather_combine(
    const float* __restrict__ in, float* __restrict__ out,
    const int* __restrict__ rp, const int* __restrict__ ebuf, float e,
    const float* __restrict__ b1, int t) {
    const int ch = t & 31;
    const int hw = t >> 5;   // 0..15
    for (int n = hw; n < ROI; n += 16) {
        int b = rp[n], en = rp[n + 1];
        float acc = 0.f;
        int j = b;
        for (; j + 3 < en; j += 4) {
            int p0 = ebuf[j], p1 = ebuf[j + 1], p2 = ebuf[j + 2], p3 = ebuf[j + 3];
            float v0 = in[p0 + ch], v1 = in[p1 + ch];
            float v2 = in[p2 + ch], v3 = in[p3 + ch];
            acc += (v0 + v1) + (v2 + v3);
        }
        for (; j < en; ++j) acc += in[ebuf[j] + ch];
        out[n * SR + ch] = leakyf(e * in[n * SR + ch] + acc + b1[ch]);
    }
}

template <bool AFFINE>
__device__ __forceinline__ void gemm_inplace(float* __restrict__ buf,
                                             const float* __restrict__ w,
                                             const float* __restrict__ bias,
                                             const float* __restrict__ sc,
                                             const float* __restrict__ sh, int t) {
    for (int u = t; u < ROI * 2; u += 512) {
        const int r0 = (u >> 2) * 2;
        const int cq = u & 3;
        float acc0[8], acc1[8];
#pragma unroll
        for (int c = 0; c < 8; c++) {
            float b = AFFINE ? bias[cq * 8 + c] : 0.f;
            acc0[c] = b;
            acc1[c] = b;
        }
        const float* row0 = &buf[r0 * SR];
        const float* row1 = row0 + SR;
        // unroll 2 ONLY: full unroll software-pipelines all 64 w-float4s
        // -> >128 VGPR -> scratch spill -> 1 GB HBM (rounds 2/3)
#pragma unroll 2
        for (int k = 0; k < CH; k += 2) {
            float2 a0 = *(const float2*)&row0[k];
            float2 a1 = *(const float2*)&row1[k];
            const float* wr0 = &w[k * CH + cq * 8];
            const float* wr1 = wr0 + CH;
            float4 wa = *(const float4*)wr0;
            float4 wb = *(const float4*)(wr0 + 4);
            float4 wc = *(const float4*)wr1;
            float4 wd = *(const float4*)(wr1 + 4);
            acc0[0] += a0.x * wa.x + a0.y * wc.x;
            acc0[1] += a0.x * wa.y + a0.y * wc.y;
            acc0[2] += a0.x * wa.z + a0.y * wc.z;
            acc0[3] += a0.x * wa.w + a0.y * wc.w;
            acc0[4] += a0.x * wb.x + a0.y * wd.x;
            acc0[5] += a0.x * wb.y + a0.y * wd.y;
            acc0[6] += a0.x * wb.z + a0.y * wd.z;
            acc0[7] += a0.x * wb.w + a0.y * wd.w;
            acc1[0] += a1.x * wa.x + a1.y * wc.x;
            acc1[1] += a1.x * wa.y + a1.y * wc.y;
            acc1[2] += a1.x * wa.z + a1.y * wc.z;
            acc1[3] += a1.x * wa.w + a1.y * wc.w;
            acc1[4] += a1.x * wb.x + a1.y * wd.x;
            acc1[5] += a1.x * wb.y + a1.y * wd.y;
            acc1[6] += a1.x * wb.z + a1.y * wd.z;
            acc1[7] += a1.x * wb.w + a1.y * wd.w;
        }
        float* o0 = &buf[r0 * SR + cq * 8];
        float* o1 = o0 + SR;
#pragma unroll
        for (int c = 0; c < 8; c += 2) {
            float h00 = acc0[c], h01 = acc0[c + 1];
            float h10 = acc1[c], h11 = acc1[c + 1];
            if (AFFINE) {
                float s0 = sc[cq * 8 + c], t0 = sh[cq * 8 + c];
                float s1 = sc[cq * 8 + c + 1], t1 = sh[cq * 8 + c + 1];
                h00 = leakyf(h00 * s0 + t0);
                h01 = leakyf(h01 * s1 + t1);
                h10 = leakyf(h10 * s0 + t0);
                h11 = leakyf(h11 * s1 + t1);
            }
            *(float2*)&o0[c] = make_float2(h00, h01);
            *(float2*)&o1[c] = make_float2(h10, h11);
        }
    }
}

__device__ __forceinline__ void pool_store(const float* __restrict__ h,
                                           float* __restrict__ psc, int t) {
    const int ch = t & 31;
    const int hw = t >> 5;
    const int wave = t >> 6;
    float s = 0.f, m = -1e30f;
    for (int n = hw; n < ROI; n += 16) {
        float v = h[n * SR + ch];
        s += v;
        m = fmaxf(m, v);
    }
    s += __shfl_down(s, 32);
    m = fmaxf(m, __shfl_down(m, 32));
    if ((t & 63) < 32) {
        psc[wave * 32 + ch] = s;
        psc[256 + wave * 32 + ch] = m;
    }
}

__device__ __forceinline__ void pool_final(const float* __restrict__ psc,
                                           float* __restrict__ zg, int t) {
    if (t < 32) {
        float s = 0.f, m = -1e30f;
#pragma unroll
        for (int wv = 0; wv < 8; wv++) {
            s += psc[wv * 32 + t];
            m = fmaxf(m, psc[256 + wv * 32 + t]);
        }
        zg[t] = m;
        zg[CH + t] = s / (float)ROI;
    }
}

// ---------------------------------------------------------------------------
// K3: fused both GIN layers + both poolings. One 512-thr block per graph.
// ---------------------------------------------------------------------------
__global__ __launch_bounds__(512, 2) void k_gin(
    const float* __restrict__ y0, const int* __restrict__ row_ptr,
    const int* __restrict__ ebuf, const float* __restrict__ eps0p,
    const float* __restrict__ b1_0, const float* __restrict__ W2_0,
    const float* __restrict__ b2_0, const float* __restrict__ bn0_g,
    const float* __restrict__ bn0_b, const float* __restrict__ bn0_m,
    const float* __restrict__ bn0_v, const float* __restrict__ eps1p,
    const float* __restrict__ W1_1, const float* __restrict__ b1_1,
    const float* __restrict__ W2_1, const float* __restrict__ b2_1,
    const float* __restrict__ bn1_g, const float* __restrict__ bn1_b,
    const float* __restrict__ bn1_m, const float* __restrict__ bn1_v,
    float* __restrict__ z) {
    __shared__ float bufA[ROI * SR];
    __shared__ float bufB[ROI * SR];
    __shared__ float w[CH * CH];
    __shared__ float prm[8 * CH];
    __shared__ float psc[512];
    __shared__ float epss[2];

    const int t = threadIdx.x;
    const int g = blockIdx.x;

    if (t < CH) {
        prm[0 * CH + t] = b1_0[t];
        prm[1 * CH + t] = b2_0[t];
        float s0 = bn0_g[t] * rsqrtf(bn0_v[t] + BN_EPS);
        prm[2 * CH + t] = s0;
        prm[3 * CH + t] = bn0_b[t] - bn0_m[t] * s0;
        prm[4 * CH + t] = b1_1[t];
        prm[5 * CH + t] = b2_1[t];
        float s1 = bn1_g[t] * rsqrtf(bn1_v[t] + BN_EPS);
        prm[6 * CH + t] = s1;
        prm[7 * CH + t] = bn1_b[t] - bn1_m[t] * s1;
    }
    if (t == 0) {
        epss[0] = 1.0f + *eps0p;
        epss[1] = 1.0f + *eps1p;
    }

    const float* yg = y0 + (size_t)g * ROI * CH;
    for (int f = t; f < (ROI * CH) / 4; f += 512) {
        float4 v = ((const float4*)yg)[f];
        int row = f >> 3, c4 = (f & 7) << 2;
        float* p = &bufA[row * SR + c4];
        *(float2*)p = make_float2(v.x, v.y);
        *(float2*)(p + 2) = make_float2(v.z, v.w);
    }
    for (int i = t; i < (CH * CH) / 4; i += 512)
        ((float4*)w)[i] = ((const float4*)W2_0)[i];
    __syncthreads();

    const int* rp = row_ptr + g * RPS;

    gather_combine(bufA, bufB, rp, ebuf, epss[0], &prm[0 * CH], t);
    __syncthreads();

    gemm_inplace<true>(bufB, w, &prm[1 * CH], &prm[2 * CH], &prm[3 * CH], t);
    __syncthreads();

    pool_store(bufB, psc, t);
    for (int i = t; i < (CH * CH) / 4; i += 512)
        ((float4*)w)[i] = ((const float4*)W1_1)[i];
    __syncthreads();

    pool_final(psc, z + (size_t)g * 128, t);
    gemm_inplace<false>(bufB, w, nullptr, nullptr, nullptr, t);
    __syncthreads();

    gather_combine(bufB, bufA, rp, ebuf, epss[1], &prm[4 * CH], t);
    for (int i = t; i < (CH * CH) / 4; i += 512)
        ((float4*)w)[i] = ((const float4*)W2_1)[i];
    __syncthreads();

    gemm_inplace<true>(bufA, w, &prm[5 * CH], &prm[6 * CH], &prm[7 * CH], t);
    __syncthreads();

    pool_store(bufA, psc, t);
    __syncthreads();
    pool_final(psc, z + (size_t)g * 128 + 64, t);
}

// ---------------------------------------------------------------------------
// K4: head MLP  z[512,128] -> 256 -> 128 -> 1
// ---------------------------------------------------------------------------
__global__ __launch_bounds__(256) void k_head(
    const float* __restrict__ z, const float* __restrict__ W1,
    const float* __restrict__ b1, const float* __restrict__ g1,
    const float* __restrict__ be1, const float* __restrict__ m1,
    const float* __restrict__ v1, const float* __restrict__ W2,
    const float* __restrict__ b2, const float* __restrict__ g2,
    const float* __restrict__ be2, const float* __restrict__ m2,
    const float* __restrict__ v2, const float* __restrict__ W3,
    const float* __restrict__ b3, float* __restrict__ out) {
    __shared__ float zr[128], z1[256], z2[128];
    const int t = threadIdx.x;
    const int g = blockIdx.x;

    if (t < 32) ((float4*)zr)[t] = ((const float4*)(z + (size_t)g * 128))[t];
    __syncthreads();
    {
        float acc = b1[t];
#pragma unroll 8
        for (int k = 0; k < 128; k++) acc += zr[k] * W1[k * 256 + t];
        float s = g1[t] * rsqrtf(v1[t] + BN_EPS);
        acc = (acc - m1[t]) * s + be1[t];
        z1[t] = leakyf(acc);
    }
    __syncthreads();
    if (t < 128) {
        float acc = b2[t];
#pragma unroll 8
        for (int k = 0; k < 256; k++) acc += z1[k] * W2[k * 128 + t];
        float s = g2[t] * rsqrtf(v2[t] + BN_EPS);
        acc = (acc - m2[t]) * s + be2[t];
        z2[t] = leakyf(acc);
    }
    __syncthreads();
    if (t < 64) {
        float v = z2[t] * W3[t] + z2[t + 64] * W3[t + 64];
        for (int offd = 32; offd; offd >>= 1) v += __shfl_down(v, offd);
        if (t == 0) out[g] = v + b3[0];
    }
}

// ---------------------------------------------------------------------------
extern "C" void kernel_launch(void* const* d_in, const int* in_sizes, int n_in,
                              void* d_out, int out_size, void* d_ws, size_t ws_size,
                              hipStream_t stream) {
    const float* x      = (const float*)d_in[0];
    const int* eidx     = (const int*)d_in[1];
    const float* eps0   = (const float*)d_in[3];
    const float* W1_0   = (const float*)d_in[4];
    const float* b1_0   = (const float*)d_in[5];
    const float* W2_0   = (const float*)d_in[6];
    const float* b2_0   = (const float*)d_in[7];
    const float* bn0_g  = (const float*)d_in[8];
    const float* bn0_b  = (const float*)d_in[9];
    const float* bn0_m  = (const float*)d_in[10];
    const float* bn0_v  = (const float*)d_in[11];
    const float* eps1   = (const float*)d_in[12];
    const float* W1_1   = (const float*)d_in[13];
    const float* b1_1   = (const float*)d_in[14];
    const float* W2_1   = (const float*)d_in[15];
    const float* b2_1   = (const float*)d_in[16];
    const float* bn1_g  = (const float*)d_in[17];
    const float* bn1_b  = (const float*)d_in[18];
    const float* bn1_m  = (const float*)d_in[19];
    const float* bn1_v  = (const float*)d_in[20];
    const float* lin1_W = (const float*)d_in[21];
    const float* lin1_b = (const float*)d_in[22];
    const float* hbn1_g = (const float*)d_in[23];
    const float* hbn1_b = (const float*)d_in[24];
    const float* hbn1_m = (const float*)d_in[25];
    const float* hbn1_v = (const float*)d_in[26];
    const float* lin2_W = (const float*)d_in[27];
    const float* lin2_b = (const float*)d_in[28];
    const float* hbn2_g = (const float*)d_in[29];
    const float* hbn2_b = (const float*)d_in[30];
    const float* hbn2_m = (const float*)d_in[31];
    const float* hbn2_v = (const float*)d_in[32];
    const float* lin3_W = (const float*)d_in[33];
    const float* lin3_b = (const float*)d_in[34];

    const int E = in_sizes[1] / 2;
    const int* src = eidx;
    const int* dst = eidx + E;

    char* ws = (char*)d_ws;
    const size_t Y0_OFF  = 0;
    const size_t Z_OFF   = (size_t)NNODES * CH * 4;          // 17,563,648
    const size_t DEG_OFF = Z_OFF + (size_t)NG * 128 * 4;
    const size_t TKT_OFF = DEG_OFF + (size_t)NNODES * 4;     // ticket right after deg
    const size_t RP_OFF  = TKT_OFF + 64;
    const size_t EB_OFF  = RP_OFF + (size_t)(NG * RPS + 4) * 4;

    float* y0    = (float*)(ws + Y0_OFF);
    float* z     = (float*)(ws + Z_OFF);
    int* deg     = (int*)(ws + DEG_OFF);   // degree -> cursor
    int* ticket  = (int*)(ws + TKT_OFF);
    int* row_ptr = (int*)(ws + RP_OFF);
    int* ebuf    = (int*)(ws + EB_OFF);

    k_gemm1<<<NNODES / 256, 256, 0, stream>>>(x, W1_0, y0);

    hipMemsetAsync(deg, 0, (size_t)NNODES * sizeof(int) + 64, stream);
    k_deg<<<1024, 256, 0, stream>>>(dst, E, deg);
    k_scan_local<<<NG, 512, 0, stream>>>(deg, ticket, row_ptr);
    k_fill<<<1024, 256, 0, stream>>>(src, dst, E, deg, ebuf);

    k_gin<<<NG, 512, 0, stream>>>(y0, row_ptr, ebuf, eps0, b1_0, W2_0, b2_0,
                                  bn0_g, bn0_b, bn0_m, bn0_v, eps1, W1_1, b1_1,
                                  W2_1, b2_1, bn1_g, bn1_b, bn1_m, bn1_v, z);

    k_head<<<NG, 256, 0, stream>>>(z, lin1_W, lin1_b, hbn1_g, hbn1_b, hbn1_m,
                                   hbn1_v, lin2_W, lin2_b, hbn2_g, hbn2_b,
                                   hbn2_m, hbn2_v, lin3_W, lin3_b,
                                   (float*)d_out);
}

// Round 4
// 518.981 us; speedup vs baseline: 1.0687x; 1.0687x over previous
//
#include <hip/hip_runtime.h>

#define ROI 268
#define NG 512
#define NNODES (NG * ROI)   // 137216
#define CH 32
#define SLOPE 0.33f
#define BN_EPS 1e-5f
#define SR 34               // k_gin LDS row stride (words)
#define SAS 258             // k_gemm1 sA k-slab stride (words): even -> b64-aligned reads;
                            // mod32=2 -> staging stores exactly 2-way (free, m136)
#define RPS (ROI + 1)       // row_ptr per-graph stride

__device__ __forceinline__ float leakyf(float v) {
    return v > 0.f ? v : SLOPE * v;
}

// ---------------------------------------------------------------------------
// K1: y0[N,32] = x[N,268] @ W1_0[268,32]  (fp32 vector GEMM)
// v4 (round 4): round-2's clean-LDS structure at 2x residency.
//  - Round-2 PMC: conflicts 44.8M->1.1M (layout fixed) but 66KB LDS -> only
//    2 blocks/CU; all pipes <18% busy -> latency-bound on the stage->sync->
//    compute serialization. Round-3 (no-LDS thread-per-row) was worse: 2.1
//    waves/SIMD, uncoalesced x, VALU 11%.
//  - Fix: W staged per-chunk (4KB, register-prefetched) instead of whole
//    (34.3KB). LDS 37.1KB -> 4 blocks/CU = 16 waves/CU; cross-block overlap
//    hides each block's barrier phases (m114).
//  - waves_per_eu(4,4): pin the 128-VGPR/4-wave tier (need ~95 VGPR). max=4
//    stops the allocator chasing 64-VGPR/8-wave (round-0 spill); LDS pads to
//    40KB to enforce 4 blocks -- harmless, that's what we want resident.
//  - Wave w owns cols 8w..8w+7 (W read wave-uniform -> SGPR broadcast, free);
//    lane l owns rows {2l,2l+1,128+2l,129+2l} (stride-1 b64 reads, free);
//    sA staging stores exactly 2-way (free).
// ---------------------------------------------------------------------------
__global__ __launch_bounds__(256)
__attribute__((amdgpu_waves_per_eu(4, 4))) void k_gemm1(
    const float* __restrict__ x, const float* __restrict__ W1,
    float* __restrict__ y0) {
    __shared__ float sW[32 * CH];        // current k-chunk of W1: 4KB
    __shared__ float sA[32 * SAS];       // k-major x chunk: 33.0KB

    const int tid = threadIdx.x;
    const int l = tid & 63;
    const int wcb = __builtin_amdgcn_readfirstlane((tid >> 6) << 3);
    const size_t rowbase = (size_t)blockIdx.x * 256;

    float acc[4][8];
#pragma unroll
    for (int r = 0; r < 4; r++)
#pragma unroll
        for (int c = 0; c < 8; c++) acc[r][c] = 0.f;

    // prefetch x chunk 0: f = i*256+tid; row=f>>3 (8 rows/wave-instr, 128B
    // per row -> coalesced); kc=(f&7)*4
    float4 pf[8];
#pragma unroll
    for (int i = 0; i < 8; i++) {
        int f = (i << 8) + tid;
        int row = f >> 3, kc = (f & 7) << 2;
        pf[i] = *(const float4*)&x[(rowbase + row) * ROI + kc];
    }
    // prefetch W chunk 0: 32x32 floats = 256 float4, one per thread
    float4 pw = ((const float4*)W1)[tid];

    int k0 = 0;
    for (int chunk = 0; chunk < 9; ++chunk) {
        const int ksize = (chunk < 8) ? 32 : 12;
        // store prefetched chunk to LDS (k-major transpose for x)
        if (ksize == 32) {
#pragma unroll
            for (int i = 0; i < 8; i++) {
                int f = (i << 8) + tid;
                int row = f >> 3, kc = (f & 7) << 2;
                sA[(kc + 0) * SAS + row] = pf[i].x;
                sA[(kc + 1) * SAS + row] = pf[i].y;
                sA[(kc + 2) * SAS + row] = pf[i].z;
                sA[(kc + 3) * SAS + row] = pf[i].w;
            }
            ((float4*)sW)[tid] = pw;
        } else {
#pragma unroll
            for (int i = 0; i < 3; i++) {
                int kc = i << 2;
                sA[(kc + 0) * SAS + tid] = pf[i].x;
                sA[(kc + 1) * SAS + tid] = pf[i].y;
                sA[(kc + 2) * SAS + tid] = pf[i].z;
                sA[(kc + 3) * SAS + tid] = pf[i].w;
            }
            if (tid < 96) ((float4*)sW)[tid] = pw;   // 12*32/4
        }
        __syncthreads();
        // issue next chunk's global loads (in flight during compute)
        if (chunk + 1 < 9) {
            const int nk0 = k0 + ksize;
            if (chunk + 1 < 8) {
#pragma unroll
                for (int i = 0; i < 8; i++) {
                    int f = (i << 8) + tid;
                    int row = f >> 3, kc = (f & 7) << 2;
                    pf[i] = *(const float4*)&x[(rowbase + row) * ROI + nk0 + kc];
                }
                pw = ((const float4*)(W1 + nk0 * CH))[tid];
            } else {
#pragma unroll
                for (int i = 0; i < 3; i++)
                    pf[i] = *(const float4*)&x[(rowbase + tid) * ROI + nk0 + (i << 2)];
                if (tid < 96) pw = ((const float4*)(W1 + nk0 * CH))[tid];
            }
        }
        const float* wp = &sW[wcb];
#pragma unroll 2
        for (int kk = 0; kk < ksize; ++kk) {
            float2 a0 = *(const float2*)&sA[kk * SAS + 2 * l];
            float2 a1 = *(const float2*)&sA[kk * SAS + 128 + 2 * l];
            float4 w0 = *(const float4*)&wp[kk * CH];
            float4 w1 = *(const float4*)&wp[kk * CH + 4];
            float av[4] = {a0.x, a0.y, a1.x, a1.y};
            float wv[8] = {w0.x, w0.y, w0.z, w0.w, w1.x, w1.y, w1.z, w1.w};
#pragma unroll
            for (int r = 0; r < 4; r++)
#pragma unroll
                for (int c = 0; c < 8; c++) acc[r][c] += av[r] * wv[c];
        }
        k0 += ksize;
        __syncthreads();
    }

    // write out: lane rows {2l,2l+1,128+2l,129+2l}, cols wcb..wcb+7
#pragma unroll
    for (int r = 0; r < 4; r++) {
        size_t row = rowbase + ((r < 2) ? (2 * l + r) : (126 + 2 * l + r));
        *(float4*)&y0[row * CH + wcb] =
            make_float4(acc[r][0], acc[r][1], acc[r][2], acc[r][3]);
        *(float4*)&y0[row * CH + wcb + 4] =
            make_float4(acc[r][4], acc[r][5], acc[r][6], acc[r][7]);
    }
}

// ---------------------------------------------------------------------------
// K2: CSR build (by dst node): deg -> per-graph scan + atomic base ticket ->
// fill. row_ptr layout [NG][ROI+1] so per-graph bases are order-free.
// ---------------------------------------------------------------------------
__global__ void k_deg(const int* __restrict__ dst, int E, int* __restrict__ deg) {
    int stride = gridDim.x * blockDim.x;
    for (int i = blockIdx.x * blockDim.x + threadIdx.x; i < E; i += stride)
        atomicAdd(&deg[dst[i]], 1);
}

__global__ __launch_bounds__(512) void k_scan_local(
    int* __restrict__ deg, int* __restrict__ ticket, int* __restrict__ row_ptr) {
    __shared__ int s[512];
    __shared__ int sbase;
    const int g = blockIdx.x, t = threadIdx.x;
    int v = (t < ROI) ? deg[g * ROI + t] : 0;
    s[t] = v;
    __syncthreads();
    for (int d = 1; d < 512; d <<= 1) {
        int u = (t >= d) ? s[t - d] : 0;
        __syncthreads();
        s[t] += u;
        __syncthreads();
    }
    if (t == 511) sbase = atomicAdd(ticket, s[511]);
    __syncthreads();
    const int base = sbase;
    if (t < ROI) {
        int exc = base + s[t] - v;
        row_ptr[g * RPS + t] = exc;
        deg[g * ROI + t] = exc;   // becomes fill cursor
    }
    if (t == 511) row_ptr[g * RPS + ROI] = base + s[511];
}

__global__ void k_fill(const int* __restrict__ src, const int* __restrict__ dst,
                       int E, int* __restrict__ rcur, int* __restrict__ ebuf) {
    int stride = gridDim.x * blockDim.x;
    for (int i = blockIdx.x * blockDim.x + threadIdx.x; i < E; i += stride) {
        int d = dst[i];
        int g = d / ROI;
        int pos = atomicAdd(&rcur[d], 1);
        ebuf[pos] = (src[i] - g * ROI) * SR;   // premultiplied LDS word offset
    }
}

// ---------------------------------------------------------------------------
// K3 helpers
// ---------------------------------------------------------------------------
__device__ __forceinline__ void gather_combine(
    const float* __restrict__ in, float* __restrict__ out,
    const int* __restrict__ rp, const int* __restrict__ ebuf, float e,
    const float* __restrict__ b1, int t) {
    const int ch = t & 31;
    const int hw = t >> 5;   // 0..15
    for (int n = hw; n < ROI; n += 16) {
        int b = rp[n], en = rp[n + 1];
        float acc = 0.f;
        int j = b;
        for (; j + 3 < en; j += 4) {
            int p0 = ebuf[j], p1 = ebuf[j + 1], p2 = ebuf[j + 2], p3 = ebuf[j + 3];
            float v0 = in[p0 + ch], v1 = in[p1 + ch];
            float v2 = in[p2 + ch], v3 = in[p3 + ch];
            acc += (v0 + v1) + (v2 + v3);
        }
        for (; j < en; ++j) acc += in[ebuf[j] + ch];
        out[n * SR + ch] = leakyf(e * in[n * SR + ch] + acc + b1[ch]);
    }
}

template <bool AFFINE>
__device__ __forceinline__ void gemm_inplace(float* __restrict__ buf,
                                             const float* __restrict__ w,
                                             const float* __restrict__ bias,
                                             const float* __restrict__ sc,
                                             const float* __restrict__ sh, int t) {
    for (int u = t; u < ROI * 2; u += 512) {
        const int r0 = (u >> 2) * 2;
        const int cq = u & 3;
        float acc0[8], acc1[8];
#pragma unroll
        for (int c = 0; c < 8; c++) {
            float b = AFFINE ? bias[cq * 8 + c] : 0.f;
            acc0[c] = b;
            acc1[c] = b;
        }
        const float* row0 = &buf[r0 * SR];
        const float* row1 = row0 + SR;
        // unroll 2 ONLY: full unroll software-pipelines all 64 w-float4s
        // -> >128 VGPR -> scratch spill -> 1 GB HBM (rounds 2/3)
#pragma unroll 2
        for (int k = 0; k < CH; k += 2) {
            float2 a0 = *(const float2*)&row0[k];
            float2 a1 = *(const float2*)&row1[k];
            const float* wr0 = &w[k * CH + cq * 8];
            const float* wr1 = wr0 + CH;
            float4 wa = *(const float4*)wr0;
            float4 wb = *(const float4*)(wr0 + 4);
            float4 wc = *(const float4*)wr1;
            float4 wd = *(const float4*)(wr1 + 4);
            acc0[0] += a0.x * wa.x + a0.y * wc.x;
            acc0[1] += a0.x * wa.y + a0.y * wc.y;
            acc0[2] += a0.x * wa.z + a0.y * wc.z;
            acc0[3] += a0.x * wa.w + a0.y * wc.w;
            acc0[4] += a0.x * wb.x + a0.y * wd.x;
            acc0[5] += a0.x * wb.y + a0.y * wd.y;
            acc0[6] += a0.x * wb.z + a0.y * wd.z;
            acc0[7] += a0.x * wb.w + a0.y * wd.w;
            acc1[0] += a1.x * wa.x + a1.y * wc.x;
            acc1[1] += a1.x * wa.y + a1.y * wc.y;
            acc1[2] += a1.x * wa.z + a1.y * wc.z;
            acc1[3] += a1.x * wa.w + a1.y * wc.w;
            acc1[4] += a1.x * wb.x + a1.y * wd.x;
            acc1[5] += a1.x * wb.y + a1.y * wd.y;
            acc1[6] += a1.x * wb.z + a1.y * wd.z;
            acc1[7] += a1.x * wb.w + a1.y * wd.w;
        }
        float* o0 = &buf[r0 * SR + cq * 8];
        float* o1 = o0 + SR;
#pragma unroll
        for (int c = 0; c < 8; c += 2) {
            float h00 = acc0[c], h01 = acc0[c + 1];
            float h10 = acc1[c], h11 = acc1[c + 1];
            if (AFFINE) {
                float s0 = sc[cq * 8 + c], t0 = sh[cq * 8 + c];
                float s1 = sc[cq * 8 + c + 1], t1 = sh[cq * 8 + c + 1];
                h00 = leakyf(h00 * s0 + t0);
                h01 = leakyf(h01 * s1 + t1);
                h10 = leakyf(h10 * s0 + t0);
                h11 = leakyf(h11 * s1 + t1);
            }
            *(float2*)&o0[c] = make_float2(h00, h01);
            *(float2*)&o1[c] = make_float2(h10, h11);
        }
    }
}

__device__ __forceinline__ void pool_store(const float* __restrict__ h,
                                           float* __restrict__ psc, int t) {
    const int ch = t & 31;
    const int hw = t >> 5;
    const int wave = t >> 6;
    float s = 0.f, m = -1e30f;
    for (int n = hw; n < ROI; n += 16) {
        float v = h[n * SR + ch];
        s += v;
        m = fmaxf(m, v);
    }
    s += __shfl_down(s, 32);
    m = fmaxf(m, __shfl_down(m, 32));
    if ((t & 63) < 32) {
        psc[wave * 32 + ch] = s;
        psc[256 + wave * 32 + ch] = m;
    }
}

__device__ __forceinline__ void pool_final(const float* __restrict__ psc,
                                           float* __restrict__ zg, int t) {
    if (t < 32) {
        float s = 0.f, m = -1e30f;
#pragma unroll
        for (int wv = 0; wv < 8; wv++) {
            s += psc[wv * 32 + t];
            m = fmaxf(m, psc[256 + wv * 32 + t]);
        }
        zg[t] = m;
        zg[CH + t] = s / (float)ROI;
    }
}

// ---------------------------------------------------------------------------
// K3: fused both GIN layers + both poolings. One 512-thr block per graph.
// ---------------------------------------------------------------------------
__global__ __launch_bounds__(512, 2) void k_gin(
    const float* __restrict__ y0, const int* __restrict__ row_ptr,
    const int* __restrict__ ebuf, const float* __restrict__ eps0p,
    const float* __restrict__ b1_0, const float* __restrict__ W2_0,
    const float* __restrict__ b2_0, const float* __restrict__ bn0_g,
    const float* __restrict__ bn0_b, const float* __restrict__ bn0_m,
    const float* __restrict__ bn0_v, const float* __restrict__ eps1p,
    const float* __restrict__ W1_1, const float* __restrict__ b1_1,
    const float* __restrict__ W2_1, const float* __restrict__ b2_1,
    const float* __restrict__ bn1_g, const float* __restrict__ bn1_b,
    const float* __restrict__ bn1_m, const float* __restrict__ bn1_v,
    float* __restrict__ z) {
    __shared__ float bufA[ROI * SR];
    __shared__ float bufB[ROI * SR];
    __shared__ float w[CH * CH];
    __shared__ float prm[8 * CH];
    __shared__ float psc[512];
    __shared__ float epss[2];

    const int t = threadIdx.x;
    const int g = blockIdx.x;

    if (t < CH) {
        prm[0 * CH + t] = b1_0[t];
        prm[1 * CH + t] = b2_0[t];
        float s0 = bn0_g[t] * rsqrtf(bn0_v[t] + BN_EPS);
        prm[2 * CH + t] = s0;
        prm[3 * CH + t] = bn0_b[t] - bn0_m[t] * s0;
        prm[4 * CH + t] = b1_1[t];
        prm[5 * CH + t] = b2_1[t];
        float s1 = bn1_g[t] * rsqrtf(bn1_v[t] + BN_EPS);
        prm[6 * CH + t] = s1;
        prm[7 * CH + t] = bn1_b[t] - bn1_m[t] * s1;
    }
    if (t == 0) {
        epss[0] = 1.0f + *eps0p;
        epss[1] = 1.0f + *eps1p;
    }

    const float* yg = y0 + (size_t)g * ROI * CH;
    for (int f = t; f < (ROI * CH) / 4; f += 512) {
        float4 v = ((const float4*)yg)[f];
        int row = f >> 3, c4 = (f & 7) << 2;
        float* p = &bufA[row * SR + c4];
        *(float2*)p = make_float2(v.x, v.y);
        *(float2*)(p + 2) = make_float2(v.z, v.w);
    }
    for (int i = t; i < (CH * CH) / 4; i += 512)
        ((float4*)w)[i] = ((const float4*)W2_0)[i];
    __syncthreads();

    const int* rp = row_ptr + g * RPS;

    gather_combine(bufA, bufB, rp, ebuf, epss[0], &prm[0 * CH], t);
    __syncthreads();

    gemm_inplace<true>(bufB, w, &prm[1 * CH], &prm[2 * CH], &prm[3 * CH], t);
    __syncthreads();

    pool_store(bufB, psc, t);
    for (int i = t; i < (CH * CH) / 4; i += 512)
        ((float4*)w)[i] = ((const float4*)W1_1)[i];
    __syncthreads();

    pool_final(psc, z + (size_t)g * 128, t);
    gemm_inplace<false>(bufB, w, nullptr, nullptr, nullptr, t);
    __syncthreads();

    gather_combine(bufB, bufA, rp, ebuf, epss[1], &prm[4 * CH], t);
    for (int i = t; i < (CH * CH) / 4; i += 512)
        ((float4*)w)[i] = ((const float4*)W2_1)[i];
    __syncthreads();

    gemm_inplace<true>(bufA, w, &prm[5 * CH], &prm[6 * CH], &prm[7 * CH], t);
    __syncthreads();

    pool_store(bufA, psc, t);
    __syncthreads();
    pool_final(psc, z + (size_t)g * 128 + 64, t);
}

// ---------------------------------------------------------------------------
// K4: head MLP  z[512,128] -> 256 -> 128 -> 1
// ---------------------------------------------------------------------------
__global__ __launch_bounds__(256) void k_head(
    const float* __restrict__ z, const float* __restrict__ W1,
    const float* __restrict__ b1, const float* __restrict__ g1,
    const float* __restrict__ be1, const float* __restrict__ m1,
    const float* __restrict__ v1, const float* __restrict__ W2,
    const float* __restrict__ b2, const float* __restrict__ g2,
    const float* __restrict__ be2, const float* __restrict__ m2,
    const float* __restrict__ v2, const float* __restrict__ W3,
    const float* __restrict__ b3, float* __restrict__ out) {
    __shared__ float zr[128], z1[256], z2[128];
    const int t = threadIdx.x;
    const int g = blockIdx.x;

    if (t < 32) ((float4*)zr)[t] = ((const float4*)(z + (size_t)g * 128))[t];
    __syncthreads();
    {
        float acc = b1[t];
#pragma unroll 8
        for (int k = 0; k < 128; k++) acc += zr[k] * W1[k * 256 + t];
        float s = g1[t] * rsqrtf(v1[t] + BN_EPS);
        acc = (acc - m1[t]) * s + be1[t];
        z1[t] = leakyf(acc);
    }
    __syncthreads();
    if (t < 128) {
        float acc = b2[t];
#pragma unroll 8
        for (int k = 0; k < 256; k++) acc += z1[k] * W2[k * 128 + t];
        float s = g2[t] * rsqrtf(v2[t] + BN_EPS);
        acc = (acc - m2[t]) * s + be2[t];
        z2[t] = leakyf(acc);
    }
    __syncthreads();
    if (t < 64) {
        float v = z2[t] * W3[t] + z2[t + 64] * W3[t + 64];
        for (int offd = 32; offd; offd >>= 1) v += __shfl_down(v, offd);
        if (t == 0) out[g] = v + b3[0];
    }
}

// ---------------------------------------------------------------------------
extern "C" void kernel_launch(void* const* d_in, const int* in_sizes, int n_in,
                              void* d_out, int out_size, void* d_ws, size_t ws_size,
                              hipStream_t stream) {
    const float* x      = (const float*)d_in[0];
    const int* eidx     = (const int*)d_in[1];
    const float* eps0   = (const float*)d_in[3];
    const float* W1_0   = (const float*)d_in[4];
    const float* b1_0   = (const float*)d_in[5];
    const float* W2_0   = (const float*)d_in[6];
    const float* b2_0   = (const float*)d_in[7];
    const float* bn0_g  = (const float*)d_in[8];
    const float* bn0_b  = (const float*)d_in[9];
    const float* bn0_m  = (const float*)d_in[10];
    const float* bn0_v  = (const float*)d_in[11];
    const float* eps1   = (const float*)d_in[12];
    const float* W1_1   = (const float*)d_in[13];
    const float* b1_1   = (const float*)d_in[14];
    const float* W2_1   = (const float*)d_in[15];
    const float* b2_1   = (const float*)d_in[16];
    const float* bn1_g  = (const float*)d_in[17];
    const float* bn1_b  = (const float*)d_in[18];
    const float* bn1_m  = (const float*)d_in[19];
    const float* bn1_v  = (const float*)d_in[20];
    const float* lin1_W = (const float*)d_in[21];
    const float* lin1_b = (const float*)d_in[22];
    const float* hbn1_g = (const float*)d_in[23];
    const float* hbn1_b = (const float*)d_in[24];
    const float* hbn1_m = (const float*)d_in[25];
    const float* hbn1_v = (const float*)d_in[26];
    const float* lin2_W = (const float*)d_in[27];
    const float* lin2_b = (const float*)d_in[28];
    const float* hbn2_g = (const float*)d_in[29];
    const float* hbn2_b = (const float*)d_in[30];
    const float* hbn2_m = (const float*)d_in[31];
    const float* hbn2_v = (const float*)d_in[32];
    const float* lin3_W = (const float*)d_in[33];
    const float* lin3_b = (const float*)d_in[34];

    const int E = in_sizes[1] / 2;
    const int* src = eidx;
    const int* dst = eidx + E;

    char* ws = (char*)d_ws;
    const size_t Y0_OFF  = 0;
    const size_t Z_OFF   = (size_t)NNODES * CH * 4;          // 17,563,648
    const size_t DEG_OFF = Z_OFF + (size_t)NG * 128 * 4;
    const size_t TKT_OFF = DEG_OFF + (size_t)NNODES * 4;     // ticket right after deg
    const size_t RP_OFF  = TKT_OFF + 64;
    const size_t EB_OFF  = RP_OFF + (size_t)(NG * RPS + 4) * 4;

    float* y0    = (float*)(ws + Y0_OFF);
    float* z     = (float*)(ws + Z_OFF);
    int* deg     = (int*)(ws + DEG_OFF);   // degree -> cursor
    int* ticket  = (int*)(ws + TKT_OFF);
    int* row_ptr = (int*)(ws + RP_OFF);
    int* ebuf    = (int*)(ws + EB_OFF);

    k_gemm1<<<NNODES / 256, 256, 0, stream>>>(x, W1_0, y0);

    hipMemsetAsync(deg, 0, (size_t)NNODES * sizeof(int) + 64, stream);
    k_deg<<<1024, 256, 0, stream>>>(dst, E, deg);
    k_scan_local<<<NG, 512, 0, stream>>>(deg, ticket, row_ptr);
    k_fill<<<1024, 256, 0, stream>>>(src, dst, E, deg, ebuf);

    k_gin<<<NG, 512, 0, stream>>>(y0, row_ptr, ebuf, eps0, b1_0, W2_0, b2_0,
                                  bn0_g, bn0_b, bn0_m, bn0_v, eps1, W1_1, b1_1,
                                  W2_1, b2_1, bn1_g, bn1_b, bn1_m, bn1_v, z);

    k_head<<<NG, 256, 0, stream>>>(z, lin1_W, lin1_b, hbn1_g, hbn1_b, hbn1_m,
                                   hbn1_v, lin2_W, lin2_b, hbn2_g, hbn2_b,
                                   hbn2_m, hbn2_v, lin3_W, lin3_b,
                                   (float*)d_out);
}

// Round 5
// 513.965 us; speedup vs baseline: 1.0792x; 1.0098x over previous
//
#include <hip/hip_runtime.h>

#define ROI 268
#define NG 512
#define NNODES (NG * ROI)   // 137216
#define CH 32
#define SLOPE 0.33f
#define BN_EPS 1e-5f
#define SR 33               // k_gin LDS row stride (words); 33 = +1 pad, and
                            // gemm row-pair stride 66 mod 32 = 2 -> 16 banks
#define SAS 258             // k_gemm1 sA k-slab stride (words)
#define RPS (ROI + 1)       // row_ptr per-graph stride
#define SECAP 2560          // staged edge cap/graph (mean 1953, sigma 44 -> +13.7s)
#define NB_DEG 512          // deg blocks in fused k_g1deg
#define NB_G1 (NNODES / 256) // 536 gemm1 blocks

typedef unsigned short u16;

__device__ __forceinline__ float leakyf(float v) {
    return v > 0.f ? v : SLOPE * v;
}

// ---------------------------------------------------------------------------
// K1+deg fused: blocks [0,NB_DEG) do degree counting (atomic-latency-bound),
// blocks [NB_DEG, NB_DEG+NB_G1) do y0 = x @ W1_0 (LDS/VALU-latency-bound).
// Independent inputs/outputs; complementary resources; 1048 blocks all
// co-resident at 4 blocks/CU -> the ~60-85us k_deg disappears from the
// critical path (round-4 PMC: both kernels <20% on every pipe).
// gemm1 body = round-4 v4 (89.7us, no spill, conflicts 1.1M).
// ---------------------------------------------------------------------------
__global__ __launch_bounds__(256)
__attribute__((amdgpu_waves_per_eu(4, 4))) void k_g1deg(
    const float* __restrict__ x, const float* __restrict__ W1,
    float* __restrict__ y0, const int* __restrict__ dst, int E,
    int* __restrict__ deg) {
    __shared__ float sW[32 * CH];        // current k-chunk of W1: 4KB
    __shared__ float sA[32 * SAS];       // k-major x chunk: 33.0KB

    if (blockIdx.x < NB_DEG) {
        // ---- degree part ----
        int stride = NB_DEG * 256;
        for (int i = blockIdx.x * 256 + threadIdx.x; i < E; i += stride)
            atomicAdd(&deg[dst[i]], 1);
        return;
    }

    // ---- gemm1 part ----
    const int tid = threadIdx.x;
    const int l = tid & 63;
    const int wcb = __builtin_amdgcn_readfirstlane((tid >> 6) << 3);
    const size_t rowbase = (size_t)(blockIdx.x - NB_DEG) * 256;

    float acc[4][8];
#pragma unroll
    for (int r = 0; r < 4; r++)
#pragma unroll
        for (int c = 0; c < 8; c++) acc[r][c] = 0.f;

    float4 pf[8];
#pragma unroll
    for (int i = 0; i < 8; i++) {
        int f = (i << 8) + tid;
        int row = f >> 3, kc = (f & 7) << 2;
        pf[i] = *(const float4*)&x[(rowbase + row) * ROI + kc];
    }
    float4 pw = ((const float4*)W1)[tid];

    int k0 = 0;
    for (int chunk = 0; chunk < 9; ++chunk) {
        const int ksize = (chunk < 8) ? 32 : 12;
        if (ksize == 32) {
#pragma unroll
            for (int i = 0; i < 8; i++) {
                int f = (i << 8) + tid;
                int row = f >> 3, kc = (f & 7) << 2;
                sA[(kc + 0) * SAS + row] = pf[i].x;
                sA[(kc + 1) * SAS + row] = pf[i].y;
                sA[(kc + 2) * SAS + row] = pf[i].z;
                sA[(kc + 3) * SAS + row] = pf[i].w;
            }
            ((float4*)sW)[tid] = pw;
        } else {
#pragma unroll
            for (int i = 0; i < 3; i++) {
                int kc = i << 2;
                sA[(kc + 0) * SAS + tid] = pf[i].x;
                sA[(kc + 1) * SAS + tid] = pf[i].y;
                sA[(kc + 2) * SAS + tid] = pf[i].z;
                sA[(kc + 3) * SAS + tid] = pf[i].w;
            }
            if (tid < 96) ((float4*)sW)[tid] = pw;   // 12*32/4
        }
        __syncthreads();
        if (chunk + 1 < 9) {
            const int nk0 = k0 + ksize;
            if (chunk + 1 < 8) {
#pragma unroll
                for (int i = 0; i < 8; i++) {
                    int f = (i << 8) + tid;
                    int row = f >> 3, kc = (f & 7) << 2;
                    pf[i] = *(const float4*)&x[(rowbase + row) * ROI + nk0 + kc];
                }
                pw = ((const float4*)(W1 + nk0 * CH))[tid];
            } else {
#pragma unroll
                for (int i = 0; i < 3; i++)
                    pf[i] = *(const float4*)&x[(rowbase + tid) * ROI + nk0 + (i << 2)];
                if (tid < 96) pw = ((const float4*)(W1 + nk0 * CH))[tid];
            }
        }
        const float* wp = &sW[wcb];
#pragma unroll 2
        for (int kk = 0; kk < ksize; ++kk) {
            float2 a0 = *(const float2*)&sA[kk * SAS + 2 * l];
            float2 a1 = *(const float2*)&sA[kk * SAS + 128 + 2 * l];
            float4 w0 = *(const float4*)&wp[kk * CH];
            float4 w1 = *(const float4*)&wp[kk * CH + 4];
            float av[4] = {a0.x, a0.y, a1.x, a1.y};
            float wv[8] = {w0.x, w0.y, w0.z, w0.w, w1.x, w1.y, w1.z, w1.w};
#pragma unroll
            for (int r = 0; r < 4; r++)
#pragma unroll
                for (int c = 0; c < 8; c++) acc[r][c] += av[r] * wv[c];
        }
        k0 += ksize;
        __syncthreads();
    }

#pragma unroll
    for (int r = 0; r < 4; r++) {
        size_t row = rowbase + ((r < 2) ? (2 * l + r) : (126 + 2 * l + r));
        *(float4*)&y0[row * CH + wcb] =
            make_float4(acc[r][0], acc[r][1], acc[r][2], acc[r][3]);
        *(float4*)&y0[row * CH + wcb + 4] =
            make_float4(acc[r][4], acc[r][5], acc[r][6], acc[r][7]);
    }
}

// ---------------------------------------------------------------------------
// K2: CSR scan + fill. ebuf is u16 (premultiplied src_local*SR <= 8811):
// halves the scattered-write footprint (4->2MB) -- round-4 PMC showed k_fill
// writing 70.6MB HBM for a 4MB buffer (cross-XCD line ping-pong).
// ---------------------------------------------------------------------------
__global__ __launch_bounds__(512) void k_scan_local(
    int* __restrict__ deg, int* __restrict__ ticket, int* __restrict__ row_ptr) {
    __shared__ int s[512];
    __shared__ int sbase;
    const int g = blockIdx.x, t = threadIdx.x;
    int v = (t < ROI) ? deg[g * ROI + t] : 0;
    s[t] = v;
    __syncthreads();
    for (int d = 1; d < 512; d <<= 1) {
        int u = (t >= d) ? s[t - d] : 0;
        __syncthreads();
        s[t] += u;
        __syncthreads();
    }
    if (t == 511) sbase = atomicAdd(ticket, s[511]);
    __syncthreads();
    const int base = sbase;
    if (t < ROI) {
        int exc = base + s[t] - v;
        row_ptr[g * RPS + t] = exc;
        deg[g * ROI + t] = exc;   // becomes fill cursor
    }
    if (t == 511) row_ptr[g * RPS + ROI] = base + s[511];
}

__global__ void k_fill(const int* __restrict__ src, const int* __restrict__ dst,
                       int E, int* __restrict__ rcur, u16* __restrict__ ebuf) {
    int stride = gridDim.x * blockDim.x;
    for (int i = blockIdx.x * blockDim.x + threadIdx.x; i < E; i += stride) {
        int d = dst[i];
        int g = d / ROI;
        int pos = atomicAdd(&rcur[d], 1);
        ebuf[pos] = (u16)((src[i] - g * ROI) * SR);   // premultiplied LDS word offset
    }
}

// ---------------------------------------------------------------------------
// K3 helpers
// ---------------------------------------------------------------------------
__device__ __forceinline__ void gather_combine(
    const float* __restrict__ in, float* __restrict__ out,
    const int* __restrict__ rpl, const u16* __restrict__ se,
    const u16* __restrict__ ebg, float e, const float* __restrict__ b1, int t) {
    const int ch = t & 31;
    const int hw = t >> 5;   // 0..15
    for (int n = hw; n < ROI; n += 16) {
        int b = rpl[n], en = rpl[n + 1];   // LDS, local edge indices
        float acc = 0.f;
        int j = b;
        for (; j + 3 < en; j += 4) {
            int p0 = (j + 0 < SECAP) ? (int)se[j + 0] : (int)ebg[j + 0];
            int p1 = (j + 1 < SECAP) ? (int)se[j + 1] : (int)ebg[j + 1];
            int p2 = (j + 2 < SECAP) ? (int)se[j + 2] : (int)ebg[j + 2];
            int p3 = (j + 3 < SECAP) ? (int)se[j + 3] : (int)ebg[j + 3];
            float v0 = in[p0 + ch], v1 = in[p1 + ch];
            float v2 = in[p2 + ch], v3 = in[p3 + ch];
            acc += (v0 + v1) + (v2 + v3);
        }
        for (; j < en; ++j) {
            int p = (j < SECAP) ? (int)se[j] : (int)ebg[j];
            acc += in[p + ch];
        }
        out[n * SR + ch] = leakyf(e * in[n * SR + ch] + acc + b1[ch]);
    }
}

template <bool AFFINE>
__device__ __forceinline__ void gemm_inplace(float* __restrict__ buf,
                                             const float* __restrict__ w,
                                             const float* __restrict__ bias,
                                             const float* __restrict__ sc,
                                             const float* __restrict__ sh, int t) {
    for (int u = t; u < ROI * 2; u += 512) {
        const int r0 = (u >> 2) * 2;
        const int cq = u & 3;
        float acc0[8], acc1[8];
#pragma unroll
        for (int c = 0; c < 8; c++) {
            float b = AFFINE ? bias[cq * 8 + c] : 0.f;
            acc0[c] = b;
            acc1[c] = b;
        }
        const float* row0 = &buf[r0 * SR];
        const float* row1 = row0 + SR;
        // unroll 2 ONLY: full unroll software-pipelines all 64 w-float4s
        // -> >128 VGPR -> scratch spill (history rounds 2/3)
#pragma unroll 2
        for (int k = 0; k < CH; k += 2) {
            float2 a0 = *(const float2*)&row0[k];
            float2 a1 = *(const float2*)&row1[k];
            const float* wr0 = &w[k * CH + cq * 8];
            const float* wr1 = wr0 + CH;
            float4 wa = *(const float4*)wr0;
            float4 wb = *(const float4*)(wr0 + 4);
            float4 wc = *(const float4*)wr1;
            float4 wd = *(const float4*)(wr1 + 4);
            acc0[0] += a0.x * wa.x + a0.y * wc.x;
            acc0[1] += a0.x * wa.y + a0.y * wc.y;
            acc0[2] += a0.x * wa.z + a0.y * wc.z;
            acc0[3] += a0.x * wa.w + a0.y * wc.w;
            acc0[4] += a0.x * wb.x + a0.y * wd.x;
            acc0[5] += a0.x * wb.y + a0.y * wd.y;
            acc0[6] += a0.x * wb.z + a0.y * wd.z;
            acc0[7] += a0.x * wb.w + a0.y * wd.w;
            acc1[0] += a1.x * wa.x + a1.y * wc.x;
            acc1[1] += a1.x * wa.y + a1.y * wc.y;
            acc1[2] += a1.x * wa.z + a1.y * wc.z;
            acc1[3] += a1.x * wa.w + a1.y * wc.w;
            acc1[4] += a1.x * wb.x + a1.y * wd.x;
            acc1[5] += a1.x * wb.y + a1.y * wd.y;
            acc1[6] += a1.x * wb.z + a1.y * wd.z;
            acc1[7] += a1.x * wb.w + a1.y * wd.w;
        }
        float* o0 = &buf[r0 * SR + cq * 8];
        float* o1 = o0 + SR;
#pragma unroll
        for (int c = 0; c < 8; c += 2) {
            float h00 = acc0[c], h01 = acc0[c + 1];
            float h10 = acc1[c], h11 = acc1[c + 1];
            if (AFFINE) {
                float s0 = sc[cq * 8 + c], t0 = sh[cq * 8 + c];
                float s1 = sc[cq * 8 + c + 1], t1 = sh[cq * 8 + c + 1];
                h00 = leakyf(h00 * s0 + t0);
                h01 = leakyf(h01 * s1 + t1);
                h10 = leakyf(h10 * s0 + t0);
                h11 = leakyf(h11 * s1 + t1);
            }
            *(float2*)&o0[c] = make_float2(h00, h01);
            *(float2*)&o1[c] = make_float2(h10, h11);
        }
    }
}

__device__ __forceinline__ void pool_store(const float* __restrict__ h,
                                           float* __restrict__ psc, int t) {
    const int ch = t & 31;
    const int hw = t >> 5;
    const int wave = t >> 6;
    float s = 0.f, m = -1e30f;
    for (int n = hw; n < ROI; n += 16) {
        float v = h[n * SR + ch];
        s += v;
        m = fmaxf(m, v);
    }
    s += __shfl_down(s, 32);
    m = fmaxf(m, __shfl_down(m, 32));
    if ((t & 63) < 32) {
        psc[wave * 32 + ch] = s;
        psc[256 + wave * 32 + ch] = m;
    }
}

__device__ __forceinline__ void pool_final(const float* __restrict__ psc,
                                           float* __restrict__ zg, int t) {
    if (t < 32) {
        float s = 0.f, m = -1e30f;
#pragma unroll
        for (int wv = 0; wv < 8; wv++) {
            s += psc[wv * 32 + t];
            m = fmaxf(m, psc[256 + wv * 32 + t]);
        }
        zg[t] = m;
        zg[CH + t] = s / (float)ROI;
    }
}

// ---------------------------------------------------------------------------
// K3: fused both GIN layers + both poolings. One 512-thr block per graph.
// v5: per-graph edge slice staged into LDS (contiguous in CSR, ~3.9KB u16),
// killing the scattered per-edge global reads in both gathers. 5.1KB union
// region `ureg` time-shares {edge slice, W tile} with cheap coalesced
// re-stages. SR 34->33 keeps total LDS at 80.0KB -> 2 blocks/CU.
// ---------------------------------------------------------------------------
__global__ __launch_bounds__(512, 2) void k_gin(
    const float* __restrict__ y0, const int* __restrict__ row_ptr,
    const u16* __restrict__ ebuf, const float* __restrict__ eps0p,
    const float* __restrict__ b1_0, const float* __restrict__ W2_0,
    const float* __restrict__ b2_0, const float* __restrict__ bn0_g,
    const float* __restrict__ bn0_b, const float* __restrict__ bn0_m,
    const float* __restrict__ bn0_v, const float* __restrict__ eps1p,
    const float* __restrict__ W1_1, const float* __restrict__ b1_1,
    const float* __restrict__ W2_1, const float* __restrict__ b2_1,
    const float* __restrict__ bn1_g, const float* __restrict__ bn1_b,
    const float* __restrict__ bn1_m, const float* __restrict__ bn1_v,
    float* __restrict__ z) {
    __shared__ float bufA[ROI * SR];     // 35376 B
    __shared__ float bufB[ROI * SR];     // 35376 B
    __shared__ float4 ureg4[SECAP / 8];  // 5120 B union: u16 edges | W tile
    __shared__ int rpl[RPS];             // 1076 B local row_ptr
    __shared__ float prm[8 * CH];        // 1024 B
    __shared__ float psc[512];           // 2048 B
    __shared__ float epss[2];

    float* uw = (float*)ureg4;
    u16* se = (u16*)ureg4;

    const int t = threadIdx.x;
    const int g = blockIdx.x;
    const int* rp_g = row_ptr + g * RPS;
    const int base = rp_g[0];
    const u16* ebg = ebuf + base;        // graph's global edge slice

    if (t < CH) {
        prm[0 * CH + t] = b1_0[t];
        prm[1 * CH + t] = b2_0[t];
        float s0 = bn0_g[t] * rsqrtf(bn0_v[t] + BN_EPS);
        prm[2 * CH + t] = s0;
        prm[3 * CH + t] = bn0_b[t] - bn0_m[t] * s0;
        prm[4 * CH + t] = b1_1[t];
        prm[5 * CH + t] = b2_1[t];
        float s1 = bn1_g[t] * rsqrtf(bn1_v[t] + BN_EPS);
        prm[6 * CH + t] = s1;
        prm[7 * CH + t] = bn1_b[t] - bn1_m[t] * s1;
    }
    if (t == 0) {
        epss[0] = 1.0f + *eps0p;
        epss[1] = 1.0f + *eps1p;
    }
    if (t <= ROI) rpl[t] = rp_g[t] - base;   // 512 threads cover 269

    // stage y0 tile
    const float* yg = y0 + (size_t)g * ROI * CH;
    for (int f = t; f < (ROI * CH) / 4; f += 512) {
        float4 v = ((const float4*)yg)[f];
        int row = f >> 3, c4 = (f & 7) << 2;
        float* p = &bufA[row * SR + c4];
        *(float2*)p = make_float2(v.x, v.y);
        *(float2*)(p + 2) = make_float2(v.z, v.w);
    }
    __syncthreads();   // rpl ready (need cnt below)

    const int cnt = rpl[ROI] < SECAP ? rpl[ROI] : SECAP;
    // stage edge slice into LDS
    for (int i = t; i < cnt; i += 512) se[i] = ebg[i];
    __syncthreads();

    gather_combine(bufA, bufB, rpl, se, ebg, epss[0], &prm[0 * CH], t);
    __syncthreads();

    if (t < 256) ((float4*)uw)[t] = ((const float4*)W2_0)[t];   // W2_0 -> ureg
    __syncthreads();

    gemm_inplace<true>(bufB, uw, &prm[1 * CH], &prm[2 * CH], &prm[3 * CH], t);
    __syncthreads();

    pool_store(bufB, psc, t);
    __syncthreads();
    pool_final(psc, z + (size_t)g * 128, t);
    if (t < 256) ((float4*)uw)[t] = ((const float4*)W1_1)[t];   // W1_1 -> ureg
    __syncthreads();

    gemm_inplace<false>(bufB, uw, nullptr, nullptr, nullptr, t);
    __syncthreads();

    for (int i = t; i < cnt; i += 512) se[i] = ebg[i];   // re-stage edges
    __syncthreads();

    gather_combine(bufB, bufA, rpl, se, ebg, epss[1], &prm[4 * CH], t);
    __syncthreads();

    if (t < 256) ((float4*)uw)[t] = ((const float4*)W2_1)[t];   // W2_1 -> ureg
    __syncthreads();

    gemm_inplace<true>(bufA, uw, &prm[5 * CH], &prm[6 * CH], &prm[7 * CH], t);
    __syncthreads();

    pool_store(bufA, psc, t);
    __syncthreads();
    pool_final(psc, z + (size_t)g * 128 + 64, t);
}

// ---------------------------------------------------------------------------
// K4: head MLP  z[512,128] -> 256 -> 128 -> 1
// ---------------------------------------------------------------------------
__global__ __launch_bounds__(256) void k_head(
    const float* __restrict__ z, const float* __restrict__ W1,
    const float* __restrict__ b1, const float* __restrict__ g1,
    const float* __restrict__ be1, const float* __restrict__ m1,
    const float* __restrict__ v1, const float* __restrict__ W2,
    const float* __restrict__ b2, const float* __restrict__ g2,
    const float* __restrict__ be2, const float* __restrict__ m2,
    const float* __restrict__ v2, const float* __restrict__ W3,
    const float* __restrict__ b3, float* __restrict__ out) {
    __shared__ float zr[128], z1[256], z2[128];
    const int t = threadIdx.x;
    const int g = blockIdx.x;

    if (t < 32) ((float4*)zr)[t] = ((const float4*)(z + (size_t)g * 128))[t];
    __syncthreads();
    {
        float acc = b1[t];
#pragma unroll 8
        for (int k = 0; k < 128; k++) acc += zr[k] * W1[k * 256 + t];
        float s = g1[t] * rsqrtf(v1[t] + BN_EPS);
        acc = (acc - m1[t]) * s + be1[t];
        z1[t] = leakyf(acc);
    }
    __syncthreads();
    if (t < 128) {
        float acc = b2[t];
#pragma unroll 8
        for (int k = 0; k < 256; k++) acc += z1[k] * W2[k * 128 + t];
        float s = g2[t] * rsqrtf(v2[t] + BN_EPS);
        acc = (acc - m2[t]) * s + be2[t];
        z2[t] = leakyf(acc);
    }
    __syncthreads();
    if (t < 64) {
        float v = z2[t] * W3[t] + z2[t + 64] * W3[t + 64];
        for (int offd = 32; offd; offd >>= 1) v += __shfl_down(v, offd);
        if (t == 0) out[g] = v + b3[0];
    }
}

// ---------------------------------------------------------------------------
extern "C" void kernel_launch(void* const* d_in, const int* in_sizes, int n_in,
                              void* d_out, int out_size, void* d_ws, size_t ws_size,
                              hipStream_t stream) {
    const float* x      = (const float*)d_in[0];
    const int* eidx     = (const int*)d_in[1];
    const float* eps0   = (const float*)d_in[3];
    const float* W1_0   = (const float*)d_in[4];
    const float* b1_0   = (const float*)d_in[5];
    const float* W2_0   = (const float*)d_in[6];
    const float* b2_0   = (const float*)d_in[7];
    const float* bn0_g  = (const float*)d_in[8];
    const float* bn0_b  = (const float*)d_in[9];
    const float* bn0_m  = (const float*)d_in[10];
    const float* bn0_v  = (const float*)d_in[11];
    const float* eps1   = (const float*)d_in[12];
    const float* W1_1   = (const float*)d_in[13];
    const float* b1_1   = (const float*)d_in[14];
    const float* W2_1   = (const float*)d_in[15];
    const float* b2_1   = (const float*)d_in[16];
    const float* bn1_g  = (const float*)d_in[17];
    const float* bn1_b  = (const float*)d_in[18];
    const float* bn1_m  = (const float*)d_in[19];
    const float* bn1_v  = (const float*)d_in[20];
    const float* lin1_W = (const float*)d_in[21];
    const float* lin1_b = (const float*)d_in[22];
    const float* hbn1_g = (const float*)d_in[23];
    const float* hbn1_b = (const float*)d_in[24];
    const float* hbn1_m = (const float*)d_in[25];
    const float* hbn1_v = (const float*)d_in[26];
    const float* lin2_W = (const float*)d_in[27];
    const float* lin2_b = (const float*)d_in[28];
    const float* hbn2_g = (const float*)d_in[29];
    const float* hbn2_b = (const float*)d_in[30];
    const float* hbn2_m = (const float*)d_in[31];
    const float* hbn2_v = (const float*)d_in[32];
    const float* lin3_W = (const float*)d_in[33];
    const float* lin3_b = (const float*)d_in[34];

    const int E = in_sizes[1] / 2;
    const int* src = eidx;
    const int* dst = eidx + E;

    char* ws = (char*)d_ws;
    const size_t Y0_OFF  = 0;
    const size_t Z_OFF   = (size_t)NNODES * CH * 4;          // 17,563,648
    const size_t DEG_OFF = Z_OFF + (size_t)NG * 128 * 4;
    const size_t TKT_OFF = DEG_OFF + (size_t)NNODES * 4;     // ticket right after deg
    const size_t RP_OFF  = TKT_OFF + 64;
    const size_t EB_OFF  = RP_OFF + (size_t)(NG * RPS + 4) * 4;

    float* y0    = (float*)(ws + Y0_OFF);
    float* z     = (float*)(ws + Z_OFF);
    int* deg     = (int*)(ws + DEG_OFF);   // degree -> cursor
    int* ticket  = (int*)(ws + TKT_OFF);
    int* row_ptr = (int*)(ws + RP_OFF);
    u16* ebuf    = (u16*)(ws + EB_OFF);

    hipMemsetAsync(deg, 0, (size_t)NNODES * sizeof(int) + 64, stream);
    k_g1deg<<<NB_DEG + NB_G1, 256, 0, stream>>>(x, W1_0, y0, dst, E, deg);
    k_scan_local<<<NG, 512, 0, stream>>>(deg, ticket, row_ptr);
    k_fill<<<1024, 256, 0, stream>>>(src, dst, E, deg, ebuf);

    k_gin<<<NG, 512, 0, stream>>>(y0, row_ptr, ebuf, eps0, b1_0, W2_0, b2_0,
                                  bn0_g, bn0_b, bn0_m, bn0_v, eps1, W1_1, b1_1,
                                  W2_1, b2_1, bn1_g, bn1_b, bn1_m, bn1_v, z);

    k_head<<<NG, 256, 0, stream>>>(z, lin1_W, lin1_b, hbn1_g, hbn1_b, hbn1_m,
                                   hbn1_v, lin2_W, lin2_b, hbn2_g, hbn2_b,
                                   hbn2_m, hbn2_v, lin3_W, lin3_b,
                                   (float*)d_out);
}

// Round 6
// 464.554 us; speedup vs baseline: 1.1940x; 1.1064x over previous
//
#include <hip/hip_runtime.h>

#define ROI 268
#define NG 512
#define NNODES (NG * ROI)   // 137216
#define CH 32
#define SLOPE 0.33f
#define BN_EPS 1e-5f
#define SR 33               // k_gin LDS row stride (words); gemm row-pair
                            // stride 66 mod 32 = 2 -> 16 banks (free-ish)
#define SAS 258             // k_fillgemm sA k-slab stride (words)
#define RPS (ROI + 1)       // row_ptr per-graph stride
#define NB_G1 (NNODES / 256) // 536 gemm1 blocks
#define NB_FILL 1024         // fill blocks in fused k_fillgemm

typedef unsigned short u16;

__device__ __forceinline__ float leakyf(float v) {
    return v > 0.f ? v : SLOPE * v;
}

// ---------------------------------------------------------------------------
// K_deg: degree histogram (standalone again). Round-5 lesson: deg was never
// a ~75us kernel (never appeared in any top-5 with cutoffs 89-133); fusing
// it with gemm1 saved ~nothing and stretched gemm1 89.7->113.
// ---------------------------------------------------------------------------
__global__ void k_deg(const int* __restrict__ dst, int E, int* __restrict__ deg) {
    int stride = gridDim.x * blockDim.x;
    for (int i = blockIdx.x * blockDim.x + threadIdx.x; i < E; i += stride)
        atomicAdd(&deg[dst[i]], 1);
}

__global__ __launch_bounds__(512) void k_scan_local(
    int* __restrict__ deg, int* __restrict__ ticket, int* __restrict__ row_ptr) {
    __shared__ int s[512];
    __shared__ int sbase;
    const int g = blockIdx.x, t = threadIdx.x;
    int v = (t < ROI) ? deg[g * ROI + t] : 0;
    s[t] = v;
    __syncthreads();
    for (int d = 1; d < 512; d <<= 1) {
        int u = (t >= d) ? s[t - d] : 0;
        __syncthreads();
        s[t] += u;
        __syncthreads();
    }
    if (t == 511) sbase = atomicAdd(ticket, s[511]);
    __syncthreads();
    const int base = sbase;
    if (t < ROI) {
        int exc = base + s[t] - v;
        row_ptr[g * RPS + t] = exc;
        deg[g * ROI + t] = exc;   // becomes fill cursor
    }
    if (t == 511) row_ptr[g * RPS + ROI] = base + s[511];
}

// ---------------------------------------------------------------------------
// K_fillgemm: the two real ~90us kernels fused -- they are independent
// (gemm1 needs only x/W1 after nothing; fill needs only scan's cursors) and
// resource-complementary:
//   fill (round-4 PMC): VALU 0.5%, HBM 10.7%, WRITE 70.7MB for a 2MB buffer
//     = ~35x scattered sub-line write amplification -> write/atomic-latency
//     bound, no compute.
//   gemm1 (round-4 PMC): VALU 17.7%, LDS-heavy, latency-bound on barriers.
// Co-resident at 4 blocks/CU they overlap (m114). Blocks [0,NB_G1) = gemm1
// (unchanged round-4 body); [NB_G1, NB_G1+NB_FILL) = fill.
// ---------------------------------------------------------------------------
__global__ __launch_bounds__(256)
__attribute__((amdgpu_waves_per_eu(4, 4))) void k_fillgemm(
    const float* __restrict__ x, const float* __restrict__ W1,
    float* __restrict__ y0, const int* __restrict__ src,
    const int* __restrict__ dst, int E, int* __restrict__ rcur,
    u16* __restrict__ ebuf) {
    __shared__ float sW[32 * CH];        // current k-chunk of W1: 4KB
    __shared__ float sA[32 * SAS];       // k-major x chunk: 33.0KB

    if (blockIdx.x >= NB_G1) {
        // ---- fill part ----
        const int stride = NB_FILL * 256;
        for (int i = (blockIdx.x - NB_G1) * 256 + threadIdx.x; i < E; i += stride) {
            int d = dst[i];
            int g = d / ROI;
            int pos = atomicAdd(&rcur[d], 1);
            ebuf[pos] = (u16)((src[i] - g * ROI) * SR);   // premult LDS word offset
        }
        return;
    }

    // ---- gemm1 part ----
    const int tid = threadIdx.x;
    const int l = tid & 63;
    const int wcb = __builtin_amdgcn_readfirstlane((tid >> 6) << 3);
    const size_t rowbase = (size_t)blockIdx.x * 256;

    float acc[4][8];
#pragma unroll
    for (int r = 0; r < 4; r++)
#pragma unroll
        for (int c = 0; c < 8; c++) acc[r][c] = 0.f;

    float4 pf[8];
#pragma unroll
    for (int i = 0; i < 8; i++) {
        int f = (i << 8) + tid;
        int row = f >> 3, kc = (f & 7) << 2;
        pf[i] = *(const float4*)&x[(rowbase + row) * ROI + kc];
    }
    float4 pw = ((const float4*)W1)[tid];

    int k0 = 0;
    for (int chunk = 0; chunk < 9; ++chunk) {
        const int ksize = (chunk < 8) ? 32 : 12;
        if (ksize == 32) {
#pragma unroll
            for (int i = 0; i < 8; i++) {
                int f = (i << 8) + tid;
                int row = f >> 3, kc = (f & 7) << 2;
                sA[(kc + 0) * SAS + row] = pf[i].x;
                sA[(kc + 1) * SAS + row] = pf[i].y;
                sA[(kc + 2) * SAS + row] = pf[i].z;
                sA[(kc + 3) * SAS + row] = pf[i].w;
            }
            ((float4*)sW)[tid] = pw;
        } else {
#pragma unroll
            for (int i = 0; i < 3; i++) {
                int kc = i << 2;
                sA[(kc + 0) * SAS + tid] = pf[i].x;
                sA[(kc + 1) * SAS + tid] = pf[i].y;
                sA[(kc + 2) * SAS + tid] = pf[i].z;
                sA[(kc + 3) * SAS + tid] = pf[i].w;
            }
            if (tid < 96) ((float4*)sW)[tid] = pw;   // 12*32/4
        }
        __syncthreads();
        if (chunk + 1 < 9) {
            const int nk0 = k0 + ksize;
            if (chunk + 1 < 8) {
#pragma unroll
                for (int i = 0; i < 8; i++) {
                    int f = (i << 8) + tid;
                    int row = f >> 3, kc = (f & 7) << 2;
                    pf[i] = *(const float4*)&x[(rowbase + row) * ROI + nk0 + kc];
                }
                pw = ((const float4*)(W1 + nk0 * CH))[tid];
            } else {
#pragma unroll
                for (int i = 0; i < 3; i++)
                    pf[i] = *(const float4*)&x[(rowbase + tid) * ROI + nk0 + (i << 2)];
                if (tid < 96) pw = ((const float4*)(W1 + nk0 * CH))[tid];
            }
        }
        const float* wp = &sW[wcb];
#pragma unroll 2
        for (int kk = 0; kk < ksize; ++kk) {
            float2 a0 = *(const float2*)&sA[kk * SAS + 2 * l];
            float2 a1 = *(const float2*)&sA[kk * SAS + 128 + 2 * l];
            float4 w0 = *(const float4*)&wp[kk * CH];
            float4 w1 = *(const float4*)&wp[kk * CH + 4];
            float av[4] = {a0.x, a0.y, a1.x, a1.y};
            float wv[8] = {w0.x, w0.y, w0.z, w0.w, w1.x, w1.y, w1.z, w1.w};
#pragma unroll
            for (int r = 0; r < 4; r++)
#pragma unroll
                for (int c = 0; c < 8; c++) acc[r][c] += av[r] * wv[c];
        }
        k0 += ksize;
        __syncthreads();
    }

#pragma unroll
    for (int r = 0; r < 4; r++) {
        size_t row = rowbase + ((r < 2) ? (2 * l + r) : (126 + 2 * l + r));
        *(float4*)&y0[row * CH + wcb] =
            make_float4(acc[r][0], acc[r][1], acc[r][2], acc[r][3]);
        *(float4*)&y0[row * CH + wcb + 4] =
            make_float4(acc[r][4], acc[r][5], acc[r][6], acc[r][7]);
    }
}

// ---------------------------------------------------------------------------
// K3 helpers. Round-6: SECAP LDS edge-staging reverted -- ebuf reads are
// uniform per half-wave (broadcast) and L1/L2-hot; staging added conditionals
// + barriers for nothing. u16 ebuf kept (halves read footprint).
// ---------------------------------------------------------------------------
__device__ __forceinline__ void gather_combine(
    const float* __restrict__ in, float* __restrict__ out,
    const int* __restrict__ rpl, const u16* __restrict__ ebg, float e,
    const float* __restrict__ b1, int t) {
    const int ch = t & 31;
    const int hw = t >> 5;   // 0..15
    for (int n = hw; n < ROI; n += 16) {
        int b = rpl[n], en = rpl[n + 1];   // local edge indices (LDS)
        float acc = 0.f;
        int j = b;
        for (; j + 3 < en; j += 4) {
            int p0 = ebg[j], p1 = ebg[j + 1], p2 = ebg[j + 2], p3 = ebg[j + 3];
            float v0 = in[p0 + ch], v1 = in[p1 + ch];
            float v2 = in[p2 + ch], v3 = in[p3 + ch];
            acc += (v0 + v1) + (v2 + v3);
        }
        for (; j < en; ++j) acc += in[ebg[j] + ch];
        out[n * SR + ch] = leakyf(e * in[n * SR + ch] + acc + b1[ch]);
    }
}

template <bool AFFINE>
__device__ __forceinline__ void gemm_inplace(float* __restrict__ buf,
                                             const float* __restrict__ w,
                                             const float* __restrict__ bias,
                                             const float* __restrict__ sc,
                                             const float* __restrict__ sh, int t) {
    for (int u = t; u < ROI * 2; u += 512) {
        const int r0 = (u >> 2) * 2;
        const int cq = u & 3;
        float acc0[8], acc1[8];
#pragma unroll
        for (int c = 0; c < 8; c++) {
            float b = AFFINE ? bias[cq * 8 + c] : 0.f;
            acc0[c] = b;
            acc1[c] = b;
        }
        const float* row0 = &buf[r0 * SR];
        const float* row1 = row0 + SR;
        // unroll 2 ONLY: full unroll software-pipelines all 64 w-float4s
        // -> >128 VGPR -> scratch spill (history rounds 2/3)
#pragma unroll 2
        for (int k = 0; k < CH; k += 2) {
            float2 a0 = *(const float2*)&row0[k];
            float2 a1 = *(const float2*)&row1[k];
            const float* wr0 = &w[k * CH + cq * 8];
            const float* wr1 = wr0 + CH;
            float4 wa = *(const float4*)wr0;
            float4 wb = *(const float4*)(wr0 + 4);
            float4 wc = *(const float4*)wr1;
            float4 wd = *(const float4*)(wr1 + 4);
            acc0[0] += a0.x * wa.x + a0.y * wc.x;
            acc0[1] += a0.x * wa.y + a0.y * wc.y;
            acc0[2] += a0.x * wa.z + a0.y * wc.z;
            acc0[3] += a0.x * wa.w + a0.y * wc.w;
            acc0[4] += a0.x * wb.x + a0.y * wd.x;
            acc0[5] += a0.x * wb.y + a0.y * wd.y;
            acc0[6] += a0.x * wb.z + a0.y * wd.z;
            acc0[7] += a0.x * wb.w + a0.y * wd.w;
            acc1[0] += a1.x * wa.x + a1.y * wc.x;
            acc1[1] += a1.x * wa.y + a1.y * wc.y;
            acc1[2] += a1.x * wa.z + a1.y * wc.z;
            acc1[3] += a1.x * wa.w + a1.y * wc.w;
            acc1[4] += a1.x * wb.x + a1.y * wd.x;
            acc1[5] += a1.x * wb.y + a1.y * wd.y;
            acc1[6] += a1.x * wb.z + a1.y * wd.z;
            acc1[7] += a1.x * wb.w + a1.y * wd.w;
        }
        float* o0 = &buf[r0 * SR + cq * 8];
        float* o1 = o0 + SR;
#pragma unroll
        for (int c = 0; c < 8; c += 2) {
            float h00 = acc0[c], h01 = acc0[c + 1];
            float h10 = acc1[c], h11 = acc1[c + 1];
            if (AFFINE) {
                float s0 = sc[cq * 8 + c], t0 = sh[cq * 8 + c];
                float s1 = sc[cq * 8 + c + 1], t1 = sh[cq * 8 + c + 1];
                h00 = leakyf(h00 * s0 + t0);
                h01 = leakyf(h01 * s1 + t1);
                h10 = leakyf(h10 * s0 + t0);
                h11 = leakyf(h11 * s1 + t1);
            }
            *(float2*)&o0[c] = make_float2(h00, h01);
            *(float2*)&o1[c] = make_float2(h10, h11);
        }
    }
}

__device__ __forceinline__ void pool_store(const float* __restrict__ h,
                                           float* __restrict__ psc, int t) {
    const int ch = t & 31;
    const int hw = t >> 5;
    const int wave = t >> 6;
    float s = 0.f, m = -1e30f;
    for (int n = hw; n < ROI; n += 16) {
        float v = h[n * SR + ch];
        s += v;
        m = fmaxf(m, v);
    }
    s += __shfl_down(s, 32);
    m = fmaxf(m, __shfl_down(m, 32));
    if ((t & 63) < 32) {
        psc[wave * 32 + ch] = s;
        psc[256 + wave * 32 + ch] = m;
    }
}

__device__ __forceinline__ void pool_final(const float* __restrict__ psc,
                                           float* __restrict__ zg, int t) {
    if (t < 32) {
        float s = 0.f, m = -1e30f;
#pragma unroll
        for (int wv = 0; wv < 8; wv++) {
            s += psc[wv * 32 + t];
            m = fmaxf(m, psc[256 + wv * 32 + t]);
        }
        zg[t] = m;
        zg[CH + t] = s / (float)ROI;
    }
}

// ---------------------------------------------------------------------------
// K3: fused both GIN layers + both poolings. One 512-thr block per graph.
// v6: round-4 structure + SR=33 + u16 ebuf (direct global reads) + rpl in
// LDS. Total LDS 79.0KB -> 2 blocks/CU.
// ---------------------------------------------------------------------------
__global__ __launch_bounds__(512, 2) void k_gin(
    const float* __restrict__ y0, const int* __restrict__ row_ptr,
    const u16* __restrict__ ebuf, const float* __restrict__ eps0p,
    const float* __restrict__ b1_0, const float* __restrict__ W2_0,
    const float* __restrict__ b2_0, const float* __restrict__ bn0_g,
    const float* __restrict__ bn0_b, const float* __restrict__ bn0_m,
    const float* __restrict__ bn0_v, const float* __restrict__ eps1p,
    const float* __restrict__ W1_1, const float* __restrict__ b1_1,
    const float* __restrict__ W2_1, const float* __restrict__ b2_1,
    const float* __restrict__ bn1_g, const float* __restrict__ bn1_b,
    const float* __restrict__ bn1_m, const float* __restrict__ bn1_v,
    float* __restrict__ z) {
    __shared__ float bufA[ROI * SR];     // 35376 B
    __shared__ float bufB[ROI * SR];     // 35376 B
    __shared__ float w[CH * CH];         // 4096 B
    __shared__ int rpl[RPS];             // 1076 B local row_ptr
    __shared__ float prm[8 * CH];        // 1024 B
    __shared__ float psc[512];           // 2048 B
    __shared__ float epss[2];

    const int t = threadIdx.x;
    const int g = blockIdx.x;
    const int* rp_g = row_ptr + g * RPS;
    const int base = rp_g[0];
    const u16* ebg = ebuf + base;        // graph's global edge slice

    if (t < CH) {
        prm[0 * CH + t] = b1_0[t];
        prm[1 * CH + t] = b2_0[t];
        float s0 = bn0_g[t] * rsqrtf(bn0_v[t] + BN_EPS);
        prm[2 * CH + t] = s0;
        prm[3 * CH + t] = bn0_b[t] - bn0_m[t] * s0;
        prm[4 * CH + t] = b1_1[t];
        prm[5 * CH + t] = b2_1[t];
        float s1 = bn1_g[t] * rsqrtf(bn1_v[t] + BN_EPS);
        prm[6 * CH + t] = s1;
        prm[7 * CH + t] = bn1_b[t] - bn1_m[t] * s1;
    }
    if (t == 0) {
        epss[0] = 1.0f + *eps0p;
        epss[1] = 1.0f + *eps1p;
    }
    if (t <= ROI) rpl[t] = rp_g[t] - base;   // 512 threads cover 269

    // stage y0 tile
    const float* yg = y0 + (size_t)g * ROI * CH;
    for (int f = t; f < (ROI * CH) / 4; f += 512) {
        float4 v = ((const float4*)yg)[f];
        int row = f >> 3, c4 = (f & 7) << 2;
        float* p = &bufA[row * SR + c4];
        *(float2*)p = make_float2(v.x, v.y);
        *(float2*)(p + 2) = make_float2(v.z, v.w);
    }
    for (int i = t; i < (CH * CH) / 4; i += 512)
        ((float4*)w)[i] = ((const float4*)W2_0)[i];
    __syncthreads();

    gather_combine(bufA, bufB, rpl, ebg, epss[0], &prm[0 * CH], t);
    __syncthreads();

    gemm_inplace<true>(bufB, w, &prm[1 * CH], &prm[2 * CH], &prm[3 * CH], t);
    __syncthreads();

    pool_store(bufB, psc, t);
    for (int i = t; i < (CH * CH) / 4; i += 512)
        ((float4*)w)[i] = ((const float4*)W1_1)[i];
    __syncthreads();

    pool_final(psc, z + (size_t)g * 128, t);
    gemm_inplace<false>(bufB, w, nullptr, nullptr, nullptr, t);
    __syncthreads();

    gather_combine(bufB, bufA, rpl, ebg, epss[1], &prm[4 * CH], t);
    for (int i = t; i < (CH * CH) / 4; i += 512)
        ((float4*)w)[i] = ((const float4*)W2_1)[i];
    __syncthreads();

    gemm_inplace<true>(bufA, w, &prm[5 * CH], &prm[6 * CH], &prm[7 * CH], t);
    __syncthreads();

    pool_store(bufA, psc, t);
    __syncthreads();
    pool_final(psc, z + (size_t)g * 128 + 64, t);
}

// ---------------------------------------------------------------------------
// K4: head MLP  z[512,128] -> 256 -> 128 -> 1
// ---------------------------------------------------------------------------
__global__ __launch_bounds__(256) void k_head(
    const float* __restrict__ z, const float* __restrict__ W1,
    const float* __restrict__ b1, const float* __restrict__ g1,
    const float* __restrict__ be1, const float* __restrict__ m1,
    const float* __restrict__ v1, const float* __restrict__ W2,
    const float* __restrict__ b2, const float* __restrict__ g2,
    const float* __restrict__ be2, const float* __restrict__ m2,
    const float* __restrict__ v2, const float* __restrict__ W3,
    const float* __restrict__ b3, float* __restrict__ out) {
    __shared__ float zr[128], z1[256], z2[128];
    const int t = threadIdx.x;
    const int g = blockIdx.x;

    if (t < 32) ((float4*)zr)[t] = ((const float4*)(z + (size_t)g * 128))[t];
    __syncthreads();
    {
        float acc = b1[t];
#pragma unroll 8
        for (int k = 0; k < 128; k++) acc += zr[k] * W1[k * 256 + t];
        float s = g1[t] * rsqrtf(v1[t] + BN_EPS);
        acc = (acc - m1[t]) * s + be1[t];
        z1[t] = leakyf(acc);
    }
    __syncthreads();
    if (t < 128) {
        float acc = b2[t];
#pragma unroll 8
        for (int k = 0; k < 256; k++) acc += z1[k] * W2[k * 128 + t];
        float s = g2[t] * rsqrtf(v2[t] + BN_EPS);
        acc = (acc - m2[t]) * s + be2[t];
        z2[t] = leakyf(acc);
    }
    __syncthreads();
    if (t < 64) {
        float v = z2[t] * W3[t] + z2[t + 64] * W3[t + 64];
        for (int offd = 32; offd; offd >>= 1) v += __shfl_down(v, offd);
        if (t == 0) out[g] = v + b3[0];
    }
}

// ---------------------------------------------------------------------------
extern "C" void kernel_launch(void* const* d_in, const int* in_sizes, int n_in,
                              void* d_out, int out_size, void* d_ws, size_t ws_size,
                              hipStream_t stream) {
    const float* x      = (const float*)d_in[0];
    const int* eidx     = (const int*)d_in[1];
    const float* eps0   = (const float*)d_in[3];
    const float* W1_0   = (const float*)d_in[4];
    const float* b1_0   = (const float*)d_in[5];
    const float* W2_0   = (const float*)d_in[6];
    const float* b2_0   = (const float*)d_in[7];
    const float* bn0_g  = (const float*)d_in[8];
    const float* bn0_b  = (const float*)d_in[9];
    const float* bn0_m  = (const float*)d_in[10];
    const float* bn0_v  = (const float*)d_in[11];
    const float* eps1   = (const float*)d_in[12];
    const float* W1_1   = (const float*)d_in[13];
    const float* b1_1   = (const float*)d_in[14];
    const float* W2_1   = (const float*)d_in[15];
    const float* b2_1   = (const float*)d_in[16];
    const float* bn1_g  = (const float*)d_in[17];
    const float* bn1_b  = (const float*)d_in[18];
    const float* bn1_m  = (const float*)d_in[19];
    const float* bn1_v  = (const float*)d_in[20];
    const float* lin1_W = (const float*)d_in[21];
    const float* lin1_b = (const float*)d_in[22];
    const float* hbn1_g = (const float*)d_in[23];
    const float* hbn1_b = (const float*)d_in[24];
    const float* hbn1_m = (const float*)d_in[25];
    const float* hbn1_v = (const float*)d_in[26];
    const float* lin2_W = (const float*)d_in[27];
    const float* lin2_b = (const float*)d_in[28];
    const float* hbn2_g = (const float*)d_in[29];
    const float* hbn2_b = (const float*)d_in[30];
    const float* hbn2_m = (const float*)d_in[31];
    const float* hbn2_v = (const float*)d_in[32];
    const float* lin3_W = (const float*)d_in[33];
    const float* lin3_b = (const float*)d_in[34];

    const int E = in_sizes[1] / 2;
    const int* src = eidx;
    const int* dst = eidx + E;

    char* ws = (char*)d_ws;
    const size_t Y0_OFF  = 0;
    const size_t Z_OFF   = (size_t)NNODES * CH * 4;          // 17,563,648
    const size_t DEG_OFF = Z_OFF + (size_t)NG * 128 * 4;
    const size_t TKT_OFF = DEG_OFF + (size_t)NNODES * 4;     // ticket right after deg
    const size_t RP_OFF  = TKT_OFF + 64;
    const size_t EB_OFF  = RP_OFF + (size_t)(NG * RPS + 4) * 4;

    float* y0    = (float*)(ws + Y0_OFF);
    float* z     = (float*)(ws + Z_OFF);
    int* deg     = (int*)(ws + DEG_OFF);   // degree -> cursor
    int* ticket  = (int*)(ws + TKT_OFF);
    int* row_ptr = (int*)(ws + RP_OFF);
    u16* ebuf    = (u16*)(ws + EB_OFF);

    hipMemsetAsync(deg, 0, (size_t)NNODES * sizeof(int) + 64, stream);
    k_deg<<<1024, 256, 0, stream>>>(dst, E, deg);
    k_scan_local<<<NG, 512, 0, stream>>>(deg, ticket, row_ptr);

    k_fillgemm<<<NB_G1 + NB_FILL, 256, 0, stream>>>(x, W1_0, y0, src, dst, E,
                                                    deg, ebuf);

    k_gin<<<NG, 512, 0, stream>>>(y0, row_ptr, ebuf, eps0, b1_0, W2_0, b2_0,
                                  bn0_g, bn0_b, bn0_m, bn0_v, eps1, W1_1, b1_1,
                                  W2_1, b2_1, bn1_g, bn1_b, bn1_m, bn1_v, z);

    k_head<<<NG, 256, 0, stream>>>(z, lin1_W, lin1_b, hbn1_g, hbn1_b, hbn1_m,
                                   hbn1_v, lin2_W, lin2_b, hbn2_g, hbn2_b,
                                   hbn2_m, hbn2_v, lin3_W, lin3_b,
                                   (float*)d_out);
}

// Round 7
// 422.093 us; speedup vs baseline: 1.3141x; 1.1006x over previous
//
#include <hip/hip_runtime.h>

#define ROI 268
#define NG 512
#define NNODES (NG * ROI)   // 137216
#define CH 32
#define SLOPE 0.33f
#define BN_EPS 1e-5f
#define SR 33               // k_gin LDS row stride (words)
#define SAS 258             // gemm sA k-slab stride (words)
#define RPS (ROI + 1)
#define CAP 2560            // per-graph edge slice capacity (mean 1953, +13.7 sigma)
#define NB_G1 (NNODES / 256) // 536 gemm blocks
#define NB_BKT 128           // bucket blocks in fused kernel

typedef unsigned short u16;
typedef unsigned int u32;

__device__ __forceinline__ float leakyf(float v) {
    return v > 0.f ? v : SLOPE * v;
}

// ---------------------------------------------------------------------------
// K1: fused gemm1 + edge-bucketing. Round-7 rationale: the CSR trio
// (deg 1M dev-atomics -> scan -> fill 1M dev-atomics, ~2 serial kernels +
// ~180us of device-atomic throughput) is replaced by per-graph bucketing
// with ~65K device atomics: per-block LDS histogram over 512 graphs, one
// range-reservation atomic per (block,graph), then contiguous-run scatter
// of packed (dst_local<<16 | src_local*SR) pairs. Runs ~15 edges -> ~2x
// write amplification (vs fill's 35x, round-4 PMC: 70.7MB for 2MB buffer).
// Bucket part aliases its 4KB of LDS onto sW (unused in that branch) so the
// static LDS stays 37376 and waves_per_eu(4,4) keeps 4 blocks/CU.
// gemm1 body unchanged (r4: 89.7us standalone; r6 fused class ~104us).
// ---------------------------------------------------------------------------
__global__ __launch_bounds__(256)
__attribute__((amdgpu_waves_per_eu(4, 4))) void k_gemmbkt(
    const float* __restrict__ x, const float* __restrict__ W1,
    float* __restrict__ y0, const int* __restrict__ src,
    const int* __restrict__ dst, int E, int* __restrict__ gcnt,
    u32* __restrict__ pairs) {
    __shared__ float sW[32 * CH];        // gemm: W chunk | bucket: hist+gb
    __shared__ float sA[32 * SAS];       // gemm: k-major x chunk

    const int tid = threadIdx.x;

    if (blockIdx.x >= NB_G1) {
        // ---- bucket part ----
        int* hist = (int*)sW;            // 512 ints
        int* gb = (int*)sW + 512;        // 512 ints (4KB total = sW exactly)
        for (int i = tid; i < 512; i += 256) hist[i] = 0;
        __syncthreads();
        const int b = blockIdx.x - NB_G1;
        const int chunk = (E + NB_BKT - 1) / NB_BKT;
        const int i0 = b * chunk;
        const int i1 = (i0 + chunk < E) ? (i0 + chunk) : E;
        for (int i = i0 + tid; i < i1; i += 256) {
            int g = dst[i] / ROI;
            atomicAdd(&hist[g], 1);
        }
        __syncthreads();
        for (int g = tid; g < 512; g += 256) {
            int h = hist[g];
            gb[g] = h ? atomicAdd(&gcnt[g], h) : 0;
            hist[g] = 0;                 // becomes local cursor
        }
        __syncthreads();
        for (int i = i0 + tid; i < i1; i += 256) {
            int d = dst[i];
            int g = d / ROI;
            int loc = atomicAdd(&hist[g], 1);
            int pos = gb[g] + loc;
            if (pos < CAP)
                pairs[(size_t)g * CAP + pos] =
                    ((u32)(d - g * ROI) << 16) | (u32)((src[i] - g * ROI) * SR);
        }
        return;
    }

    // ---- gemm1 part (unchanged r4 body) ----
    const int l = tid & 63;
    const int wcb = __builtin_amdgcn_readfirstlane((tid >> 6) << 3);
    const size_t rowbase = (size_t)blockIdx.x * 256;

    float acc[4][8];
#pragma unroll
    for (int r = 0; r < 4; r++)
#pragma unroll
        for (int c = 0; c < 8; c++) acc[r][c] = 0.f;

    float4 pf[8];
#pragma unroll
    for (int i = 0; i < 8; i++) {
        int f = (i << 8) + tid;
        int row = f >> 3, kc = (f & 7) << 2;
        pf[i] = *(const float4*)&x[(rowbase + row) * ROI + kc];
    }
    float4 pw = ((const float4*)W1)[tid];

    int k0 = 0;
    for (int chunk = 0; chunk < 9; ++chunk) {
        const int ksize = (chunk < 8) ? 32 : 12;
        if (ksize == 32) {
#pragma unroll
            for (int i = 0; i < 8; i++) {
                int f = (i << 8) + tid;
                int row = f >> 3, kc = (f & 7) << 2;
                sA[(kc + 0) * SAS + row] = pf[i].x;
                sA[(kc + 1) * SAS + row] = pf[i].y;
                sA[(kc + 2) * SAS + row] = pf[i].z;
                sA[(kc + 3) * SAS + row] = pf[i].w;
            }
            ((float4*)sW)[tid] = pw;
        } else {
#pragma unroll
            for (int i = 0; i < 3; i++) {
                int kc = i << 2;
                sA[(kc + 0) * SAS + tid] = pf[i].x;
                sA[(kc + 1) * SAS + tid] = pf[i].y;
                sA[(kc + 2) * SAS + tid] = pf[i].z;
                sA[(kc + 3) * SAS + tid] = pf[i].w;
            }
            if (tid < 96) ((float4*)sW)[tid] = pw;   // 12*32/4
        }
        __syncthreads();
        if (chunk + 1 < 9) {
            const int nk0 = k0 + ksize;
            if (chunk + 1 < 8) {
#pragma unroll
                for (int i = 0; i < 8; i++) {
                    int f = (i << 8) + tid;
                    int row = f >> 3, kc = (f & 7) << 2;
                    pf[i] = *(const float4*)&x[(rowbase + row) * ROI + nk0 + kc];
                }
                pw = ((const float4*)(W1 + nk0 * CH))[tid];
            } else {
#pragma unroll
                for (int i = 0; i < 3; i++)
                    pf[i] = *(const float4*)&x[(rowbase + tid) * ROI + nk0 + (i << 2)];
                if (tid < 96) pw = ((const float4*)(W1 + nk0 * CH))[tid];
            }
        }
        const float* wp = &sW[wcb];
#pragma unroll 2
        for (int kk = 0; kk < ksize; ++kk) {
            float2 a0 = *(const float2*)&sA[kk * SAS + 2 * l];
            float2 a1 = *(const float2*)&sA[kk * SAS + 128 + 2 * l];
            float4 w0 = *(const float4*)&wp[kk * CH];
            float4 w1 = *(const float4*)&wp[kk * CH + 4];
            float av[4] = {a0.x, a0.y, a1.x, a1.y};
            float wv[8] = {w0.x, w0.y, w0.z, w0.w, w1.x, w1.y, w1.z, w1.w};
#pragma unroll
            for (int r = 0; r < 4; r++)
#pragma unroll
                for (int c = 0; c < 8; c++) acc[r][c] += av[r] * wv[c];
        }
        k0 += ksize;
        __syncthreads();
    }

#pragma unroll
    for (int r = 0; r < 4; r++) {
        size_t row = rowbase + ((r < 2) ? (2 * l + r) : (126 + 2 * l + r));
        *(float4*)&y0[row * CH + wcb] =
            make_float4(acc[r][0], acc[r][1], acc[r][2], acc[r][3]);
        *(float4*)&y0[row * CH + wcb + 4] =
            make_float4(acc[r][4], acc[r][5], acc[r][6], acc[r][7]);
    }
}

// ---------------------------------------------------------------------------
// K3 helpers (gather/gemm/pool unchanged from r6)
// ---------------------------------------------------------------------------
__device__ __forceinline__ void gather_combine(
    const float* __restrict__ in, float* __restrict__ out,
    const int* __restrict__ rpl, const u16* __restrict__ ebg, float e,
    const float* __restrict__ b1, int t) {
    const int ch = t & 31;
    const int hw = t >> 5;   // 0..15
    for (int n = hw; n < ROI; n += 16) {
        int b = rpl[n], en = rpl[n + 1];
        float acc = 0.f;
        int j = b;
        for (; j + 3 < en; j += 4) {
            int p0 = ebg[j], p1 = ebg[j + 1], p2 = ebg[j + 2], p3 = ebg[j + 3];
            float v0 = in[p0 + ch], v1 = in[p1 + ch];
            float v2 = in[p2 + ch], v3 = in[p3 + ch];
            acc += (v0 + v1) + (v2 + v3);
        }
        for (; j < en; ++j) acc += in[ebg[j] + ch];
        out[n * SR + ch] = leakyf(e * in[n * SR + ch] + acc + b1[ch]);
    }
}

template <bool AFFINE>
__device__ __forceinline__ void gemm_inplace(float* __restrict__ buf,
                                             const float* __restrict__ w,
                                             const float* __restrict__ bias,
                                             const float* __restrict__ sc,
                                             const float* __restrict__ sh, int t) {
    for (int u = t; u < ROI * 2; u += 512) {
        const int r0 = (u >> 2) * 2;
        const int cq = u & 3;
        float acc0[8], acc1[8];
#pragma unroll
        for (int c = 0; c < 8; c++) {
            float b = AFFINE ? bias[cq * 8 + c] : 0.f;
            acc0[c] = b;
            acc1[c] = b;
        }
        const float* row0 = &buf[r0 * SR];
        const float* row1 = row0 + SR;
        // unroll 2 ONLY: full unroll -> >128 VGPR -> scratch spill (history)
#pragma unroll 2
        for (int k = 0; k < CH; k += 2) {
            float2 a0 = *(const float2*)&row0[k];
            float2 a1 = *(const float2*)&row1[k];
            const float* wr0 = &w[k * CH + cq * 8];
            const float* wr1 = wr0 + CH;
            float4 wa = *(const float4*)wr0;
            float4 wb = *(const float4*)(wr0 + 4);
            float4 wc = *(const float4*)wr1;
            float4 wd = *(const float4*)(wr1 + 4);
            acc0[0] += a0.x * wa.x + a0.y * wc.x;
            acc0[1] += a0.x * wa.y + a0.y * wc.y;
            acc0[2] += a0.x * wa.z + a0.y * wc.z;
            acc0[3] += a0.x * wa.w + a0.y * wc.w;
            acc0[4] += a0.x * wb.x + a0.y * wd.x;
            acc0[5] += a0.x * wb.y + a0.y * wd.y;
            acc0[6] += a0.x * wb.z + a0.y * wd.z;
            acc0[7] += a0.x * wb.w + a0.y * wd.w;
            acc1[0] += a1.x * wa.x + a1.y * wc.x;
            acc1[1] += a1.x * wa.y + a1.y * wc.y;
            acc1[2] += a1.x * wa.z + a1.y * wc.z;
            acc1[3] += a1.x * wa.w + a1.y * wc.w;
            acc1[4] += a1.x * wb.x + a1.y * wd.x;
            acc1[5] += a1.x * wb.y + a1.y * wd.y;
            acc1[6] += a1.x * wb.z + a1.y * wd.z;
            acc1[7] += a1.x * wb.w + a1.y * wd.w;
        }
        float* o0 = &buf[r0 * SR + cq * 8];
        float* o1 = o0 + SR;
#pragma unroll
        for (int c = 0; c < 8; c += 2) {
            float h00 = acc0[c], h01 = acc0[c + 1];
            float h10 = acc1[c], h11 = acc1[c + 1];
            if (AFFINE) {
                float s0 = sc[cq * 8 + c], t0 = sh[cq * 8 + c];
                float s1 = sc[cq * 8 + c + 1], t1 = sh[cq * 8 + c + 1];
                h00 = leakyf(h00 * s0 + t0);
                h01 = leakyf(h01 * s1 + t1);
                h10 = leakyf(h10 * s0 + t0);
                h11 = leakyf(h11 * s1 + t1);
            }
            *(float2*)&o0[c] = make_float2(h00, h01);
            *(float2*)&o1[c] = make_float2(h10, h11);
        }
    }
}

__device__ __forceinline__ void pool_store(const float* __restrict__ h,
                                           float* __restrict__ psc, int t) {
    const int ch = t & 31;
    const int hw = t >> 5;
    const int wave = t >> 6;
    float s = 0.f, m = -1e30f;
    for (int n = hw; n < ROI; n += 16) {
        float v = h[n * SR + ch];
        s += v;
        m = fmaxf(m, v);
    }
    s += __shfl_down(s, 32);
    m = fmaxf(m, __shfl_down(m, 32));
    if ((t & 63) < 32) {
        psc[wave * 32 + ch] = s;
        psc[256 + wave * 32 + ch] = m;
    }
}

__device__ __forceinline__ void pool_final(const float* __restrict__ psc,
                                           float* __restrict__ zg, int t) {
    if (t < 32) {
        float s = 0.f, m = -1e30f;
#pragma unroll
        for (int wv = 0; wv < 8; wv++) {
            s += psc[wv * 32 + t];
            m = fmaxf(m, psc[256 + wv * 32 + t]);
        }
        zg[t] = m;
        zg[CH + t] = s / (float)ROI;
    }
}

// ---------------------------------------------------------------------------
// K3: fused GIN layers + poolings. v7: builds per-node CSR in-LDS from the
// graph's unordered pair slice: LDS hist -> 512-wide scan (in psc region) ->
// scatter sorted src-offsets to the graph's global ebuf slice (same-block
// write->read, L2-local), then the unchanged r6 gather/gemm/pool path.
// LDS: 2x35376 + 4096(w) + 1076(rpl) + 1024(prm) + 2048(psc/scan/cur) ~79KB
// -> 2 blocks/CU.
// ---------------------------------------------------------------------------
__global__ __launch_bounds__(512, 2) void k_gin(
    const float* __restrict__ y0, const int* __restrict__ gcnt,
    const u32* __restrict__ pairs, u16* __restrict__ ebuf,
    const float* __restrict__ eps0p,
    const float* __restrict__ b1_0, const float* __restrict__ W2_0,
    const float* __restrict__ b2_0, const float* __restrict__ bn0_g,
    const float* __restrict__ bn0_b, const float* __restrict__ bn0_m,
    const float* __restrict__ bn0_v, const float* __restrict__ eps1p,
    const float* __restrict__ W1_1, const float* __restrict__ b1_1,
    const float* __restrict__ W2_1, const float* __restrict__ b2_1,
    const float* __restrict__ bn1_g, const float* __restrict__ bn1_b,
    const float* __restrict__ bn1_m, const float* __restrict__ bn1_v,
    float* __restrict__ z) {
    __shared__ float bufA[ROI * SR];     // 35376 B
    __shared__ float bufB[ROI * SR];     // 35376 B
    __shared__ float w[CH * CH];         // 4096 B
    __shared__ int rpl[RPS];             // 1076 B: hist -> exclusive bases
    __shared__ float prm[8 * CH];        // 1024 B
    __shared__ float psc[512];           // 2048 B: scan buf | cursors | pool
    __shared__ float epss[2];

    const int t = threadIdx.x;
    const int g = blockIdx.x;
    const u32* pg = pairs + (size_t)g * CAP;
    u16* ebg = ebuf + (size_t)g * CAP;
    const int cnt = (gcnt[g] < CAP) ? gcnt[g] : CAP;

    if (t < CH) {
        prm[0 * CH + t] = b1_0[t];
        prm[1 * CH + t] = b2_0[t];
        float s0 = bn0_g[t] * rsqrtf(bn0_v[t] + BN_EPS);
        prm[2 * CH + t] = s0;
        prm[3 * CH + t] = bn0_b[t] - bn0_m[t] * s0;
        prm[4 * CH + t] = b1_1[t];
        prm[5 * CH + t] = b2_1[t];
        float s1 = bn1_g[t] * rsqrtf(bn1_v[t] + BN_EPS);
        prm[6 * CH + t] = s1;
        prm[7 * CH + t] = bn1_b[t] - bn1_m[t] * s1;
    }
    if (t == 0) {
        epss[0] = 1.0f + *eps0p;
        epss[1] = 1.0f + *eps1p;
    }
    if (t < RPS) rpl[t] = 0;

    // stage y0 tile
    const float* yg = y0 + (size_t)g * ROI * CH;
    for (int f = t; f < (ROI * CH) / 4; f += 512) {
        float4 v = ((const float4*)yg)[f];
        int row = f >> 3, c4 = (f & 7) << 2;
        float* p = &bufA[row * SR + c4];
        *(float2*)p = make_float2(v.x, v.y);
        *(float2*)(p + 2) = make_float2(v.z, v.w);
    }
    for (int i = t; i < (CH * CH) / 4; i += 512)
        ((float4*)w)[i] = ((const float4*)W2_0)[i];
    __syncthreads();

    // ---- in-LDS CSR build ----
    for (int i = t; i < cnt; i += 512) atomicAdd(&rpl[pg[i] >> 16], 1);
    __syncthreads();
    int* s = (int*)psc;
    int v = (t < ROI) ? rpl[t] : 0;
    s[t] = v;
    __syncthreads();
    for (int d = 1; d < 512; d <<= 1) {
        int u = (t >= d) ? s[t - d] : 0;
        __syncthreads();
        s[t] += u;
        __syncthreads();
    }
    int inc = s[t];
    if (t < ROI) rpl[t] = inc - v;       // exclusive base
    if (t == 511) rpl[ROI] = inc;        // total
    __syncthreads();
    int* cur = (int*)psc;
    if (t < ROI) cur[t] = rpl[t];
    __syncthreads();
    for (int i = t; i < cnt; i += 512) {
        u32 p = pg[i];
        int pos = atomicAdd(&cur[p >> 16], 1);
        ebg[pos] = (u16)(p & 0xffffu);
    }
    __syncthreads();

    // ---- layer 0 ----
    gather_combine(bufA, bufB, rpl, ebg, epss[0], &prm[0 * CH], t);
    __syncthreads();

    gemm_inplace<true>(bufB, w, &prm[1 * CH], &prm[2 * CH], &prm[3 * CH], t);
    __syncthreads();

    pool_store(bufB, psc, t);
    for (int i = t; i < (CH * CH) / 4; i += 512)
        ((float4*)w)[i] = ((const float4*)W1_1)[i];
    __syncthreads();

    pool_final(psc, z + (size_t)g * 128, t);
    gemm_inplace<false>(bufB, w, nullptr, nullptr, nullptr, t);
    __syncthreads();

    // ---- layer 1 ----
    gather_combine(bufB, bufA, rpl, ebg, epss[1], &prm[4 * CH], t);
    for (int i = t; i < (CH * CH) / 4; i += 512)
        ((float4*)w)[i] = ((const float4*)W2_1)[i];
    __syncthreads();

    gemm_inplace<true>(bufA, w, &prm[5 * CH], &prm[6 * CH], &prm[7 * CH], t);
    __syncthreads();

    pool_store(bufA, psc, t);
    __syncthreads();
    pool_final(psc, z + (size_t)g * 128 + 64, t);
}

// ---------------------------------------------------------------------------
// K4: head MLP  z[512,128] -> 256 -> 128 -> 1
// ---------------------------------------------------------------------------
__global__ __launch_bounds__(256) void k_head(
    const float* __restrict__ z, const float* __restrict__ W1,
    const float* __restrict__ b1, const float* __restrict__ g1,
    const float* __restrict__ be1, const float* __restrict__ m1,
    const float* __restrict__ v1, const float* __restrict__ W2,
    const float* __restrict__ b2, const float* __restrict__ g2,
    const float* __restrict__ be2, const float* __restrict__ m2,
    const float* __restrict__ v2, const float* __restrict__ W3,
    const float* __restrict__ b3, float* __restrict__ out) {
    __shared__ float zr[128], z1[256], z2[128];
    const int t = threadIdx.x;
    const int g = blockIdx.x;

    if (t < 32) ((float4*)zr)[t] = ((const float4*)(z + (size_t)g * 128))[t];
    __syncthreads();
    {
        float acc = b1[t];
#pragma unroll 8
        for (int k = 0; k < 128; k++) acc += zr[k] * W1[k * 256 + t];
        float s = g1[t] * rsqrtf(v1[t] + BN_EPS);
        acc = (acc - m1[t]) * s + be1[t];
        z1[t] = leakyf(acc);
    }
    __syncthreads();
    if (t < 128) {
        float acc = b2[t];
#pragma unroll 8
        for (int k = 0; k < 256; k++) acc += z1[k] * W2[k * 128 + t];
        float s = g2[t] * rsqrtf(v2[t] + BN_EPS);
        acc = (acc - m2[t]) * s + be2[t];
        z2[t] = leakyf(acc);
    }
    __syncthreads();
    if (t < 64) {
        float v = z2[t] * W3[t] + z2[t + 64] * W3[t + 64];
        for (int offd = 32; offd; offd >>= 1) v += __shfl_down(v, offd);
        if (t == 0) out[g] = v + b3[0];
    }
}

// ---------------------------------------------------------------------------
extern "C" void kernel_launch(void* const* d_in, const int* in_sizes, int n_in,
                              void* d_out, int out_size, void* d_ws, size_t ws_size,
                              hipStream_t stream) {
    const float* x      = (const float*)d_in[0];
    const int* eidx     = (const int*)d_in[1];
    const float* eps0   = (const float*)d_in[3];
    const float* W1_0   = (const float*)d_in[4];
    const float* b1_0   = (const float*)d_in[5];
    const float* W2_0   = (const float*)d_in[6];
    const float* b2_0   = (const float*)d_in[7];
    const float* bn0_g  = (const float*)d_in[8];
    const float* bn0_b  = (const float*)d_in[9];
    const float* bn0_m  = (const float*)d_in[10];
    const float* bn0_v  = (const float*)d_in[11];
    const float* eps1   = (const float*)d_in[12];
    const float* W1_1   = (const float*)d_in[13];
    const float* b1_1   = (const float*)d_in[14];
    const float* W2_1   = (const float*)d_in[15];
    const float* b2_1   = (const float*)d_in[16];
    const float* bn1_g  = (const float*)d_in[17];
    const float* bn1_b  = (const float*)d_in[18];
    const float* bn1_m  = (const float*)d_in[19];
    const float* bn1_v  = (const float*)d_in[20];
    const float* lin1_W = (const float*)d_in[21];
    const float* lin1_b = (const float*)d_in[22];
    const float* hbn1_g = (const float*)d_in[23];
    const float* hbn1_b = (const float*)d_in[24];
    const float* hbn1_m = (const float*)d_in[25];
    const float* hbn1_v = (const float*)d_in[26];
    const float* lin2_W = (const float*)d_in[27];
    const float* lin2_b = (const float*)d_in[28];
    const float* hbn2_g = (const float*)d_in[29];
    const float* hbn2_b = (const float*)d_in[30];
    const float* hbn2_m = (const float*)d_in[31];
    const float* hbn2_v = (const float*)d_in[32];
    const float* lin3_W = (const float*)d_in[33];
    const float* lin3_b = (const float*)d_in[34];

    const int E = in_sizes[1] / 2;
    const int* src = eidx;
    const int* dst = eidx + E;

    char* ws = (char*)d_ws;
    const size_t Y0_OFF = 0;
    const size_t Z_OFF  = (size_t)NNODES * CH * 4;           // 17,563,648
    const size_t GC_OFF = Z_OFF + (size_t)NG * 128 * 4;      // +262,144
    const size_t PR_OFF = GC_OFF + 2048;
    const size_t EB_OFF = PR_OFF + (size_t)NG * CAP * 4;     // pairs 5.24MB

    float* y0  = (float*)(ws + Y0_OFF);
    float* z   = (float*)(ws + Z_OFF);
    int* gcnt  = (int*)(ws + GC_OFF);
    u32* pairs = (u32*)(ws + PR_OFF);
    u16* ebuf  = (u16*)(ws + EB_OFF);

    hipMemsetAsync(gcnt, 0, 2048, stream);
    k_gemmbkt<<<NB_G1 + NB_BKT, 256, 0, stream>>>(x, W1_0, y0, src, dst, E,
                                                  gcnt, pairs);

    k_gin<<<NG, 512, 0, stream>>>(y0, gcnt, pairs, ebuf, eps0, b1_0, W2_0,
                                  b2_0, bn0_g, bn0_b, bn0_m, bn0_v, eps1,
                                  W1_1, b1_1, W2_1, b2_1, bn1_g, bn1_b,
                                  bn1_m, bn1_v, z);

    k_head<<<NG, 256, 0, stream>>>(z, lin1_W, lin1_b, hbn1_g, hbn1_b, hbn1_m,
                                   hbn1_v, lin2_W, lin2_b, hbn2_g, hbn2_b,
                                   hbn2_m, hbn2_v, lin3_W, lin3_b,
                                   (float*)d_out);
}

// Round 8
// 412.480 us; speedup vs baseline: 1.3447x; 1.0233x over previous
//
#include <hip/hip_runtime.h>

#define ROI 268
#define NG 512
#define NNODES (NG * ROI)   // 137216
#define CH 32
#define SLOPE 0.33f
#define BN_EPS 1e-5f
#define SR 33               // k_gin LDS row stride (words)
#define SAS2 130            // gemm sA k-slab stride (128 rows + pad; mod32=2)
#define RPS (ROI + 1)
#define CAP 2560            // per-graph edge slice capacity (mean 1953, +13.7 sigma)
#define NB_G1 (NNODES / 128) // 1072 gemm blocks (128 rows each)
#define NB_BKT 128           // bucket blocks in fused kernel

typedef unsigned short u16;
typedef unsigned int u32;

__device__ __forceinline__ float leakyf(float v) {
    return v > 0.f ? v : SLOPE * v;
}

// ---------------------------------------------------------------------------
// K1: fused gemm1 + edge-bucketing.
// v8 gemm: 128-row blocks. Round-7 PMC isolated the limiter: grid 664 blocks
// = 2.6/CU average (occupancy 21%, VALU 17%) -- the machine was never full.
// 1072+128 = 1200 blocks ~ 4.7/CU, all co-resident (LDS 20.7KB -> cap 7).
// Per-thread state halves (acc[2][8], pf[4]) -> 64-VGPR tier fits w/o spill
// (r4 fit 2x this state in 64). waves_per_eu(4,8): min4 = VGPR<=128 safe,
// max8 = no LDS padding (r1 lesson). LDS access patterns carried over:
// stores exactly 2-way, reads stride-1 b64, W wave-uniform broadcast.
// Bucket part unchanged (r7: ~65K dev atomics, ~2x write amp).
// ---------------------------------------------------------------------------
__global__ __launch_bounds__(256)
__attribute__((amdgpu_waves_per_eu(4, 8))) void k_gemmbkt(
    const float* __restrict__ x, const float* __restrict__ W1,
    float* __restrict__ y0, const int* __restrict__ src,
    const int* __restrict__ dst, int E, int* __restrict__ gcnt,
    u32* __restrict__ pairs) {
    __shared__ float sW[32 * CH];        // gemm: W chunk | bucket: hist+gb
    __shared__ float sA[32 * SAS2];      // gemm: k-major x chunk (16.6KB)

    const int tid = threadIdx.x;

    if (blockIdx.x >= NB_G1) {
        // ---- bucket part ----
        int* hist = (int*)sW;            // 512 ints
        int* gb = (int*)sW + 512;        // 512 ints (4KB = sW exactly)
        for (int i = tid; i < 512; i += 256) hist[i] = 0;
        __syncthreads();
        const int b = blockIdx.x - NB_G1;
        const int chunk = (E + NB_BKT - 1) / NB_BKT;
        const int i0 = b * chunk;
        const int i1 = (i0 + chunk < E) ? (i0 + chunk) : E;
        for (int i = i0 + tid; i < i1; i += 256) {
            int g = dst[i] / ROI;
            atomicAdd(&hist[g], 1);
        }
        __syncthreads();
        for (int g = tid; g < 512; g += 256) {
            int h = hist[g];
            gb[g] = h ? atomicAdd(&gcnt[g], h) : 0;
            hist[g] = 0;                 // becomes local cursor
        }
        __syncthreads();
        for (int i = i0 + tid; i < i1; i += 256) {
            int d = dst[i];
            int g = d / ROI;
            int loc = atomicAdd(&hist[g], 1);
            int pos = gb[g] + loc;
            if (pos < CAP)
                pairs[(size_t)g * CAP + pos] =
                    ((u32)(d - g * ROI) << 16) | (u32)((src[i] - g * ROI) * SR);
        }
        return;
    }

    // ---- gemm1 part: 128 rows/block ----
    const int l = tid & 63;
    const int wcb = __builtin_amdgcn_readfirstlane((tid >> 6) << 3);
    const size_t rowbase = (size_t)blockIdx.x * 128;

    float acc[2][8];
#pragma unroll
    for (int r = 0; r < 2; r++)
#pragma unroll
        for (int c = 0; c < 8; c++) acc[r][c] = 0.f;

    // prefetch x chunk 0: 128 rows x 32 k = 1024 float4, 4/thread.
    // f=i*256+tid: row=f>>3 (8 lanes/row x 16B = 128B contiguous), kc=(f&7)*4
    float4 pf[4];
#pragma unroll
    for (int i = 0; i < 4; i++) {
        int f = (i << 8) + tid;
        int row = f >> 3, kc = (f & 7) << 2;
        pf[i] = *(const float4*)&x[(rowbase + row) * ROI + kc];
    }
    float4 pw = ((const float4*)W1)[tid];

    int k0 = 0;
    for (int chunk = 0; chunk < 9; ++chunk) {
        const int ksize = (chunk < 8) ? 32 : 12;
        if (ksize == 32) {
#pragma unroll
            for (int i = 0; i < 4; i++) {
                int f = (i << 8) + tid;
                int row = f >> 3, kc = (f & 7) << 2;
                sA[(kc + 0) * SAS2 + row] = pf[i].x;
                sA[(kc + 1) * SAS2 + row] = pf[i].y;
                sA[(kc + 2) * SAS2 + row] = pf[i].z;
                sA[(kc + 3) * SAS2 + row] = pf[i].w;
            }
            ((float4*)sW)[tid] = pw;
        } else {
            if (tid < 128) {
#pragma unroll
                for (int i = 0; i < 3; i++) {
                    int kc = i << 2;
                    sA[(kc + 0) * SAS2 + tid] = pf[i].x;
                    sA[(kc + 1) * SAS2 + tid] = pf[i].y;
                    sA[(kc + 2) * SAS2 + tid] = pf[i].z;
                    sA[(kc + 3) * SAS2 + tid] = pf[i].w;
                }
            }
            if (tid < 96) ((float4*)sW)[tid] = pw;   // 12*32/4
        }
        __syncthreads();
        if (chunk + 1 < 9) {
            const int nk0 = k0 + ksize;
            if (chunk + 1 < 8) {
#pragma unroll
                for (int i = 0; i < 4; i++) {
                    int f = (i << 8) + tid;
                    int row = f >> 3, kc = (f & 7) << 2;
                    pf[i] = *(const float4*)&x[(rowbase + row) * ROI + nk0 + kc];
                }
                pw = ((const float4*)(W1 + nk0 * CH))[tid];
            } else {
                if (tid < 128) {
#pragma unroll
                    for (int i = 0; i < 3; i++)
                        pf[i] = *(const float4*)&x[(rowbase + tid) * ROI + nk0 + (i << 2)];
                }
                if (tid < 96) pw = ((const float4*)(W1 + nk0 * CH))[tid];
            }
        }
        const float* wp = &sW[wcb];
#pragma unroll 2
        for (int kk = 0; kk < ksize; ++kk) {
            float2 a0 = *(const float2*)&sA[kk * SAS2 + 2 * l];
            float4 w0 = *(const float4*)&wp[kk * CH];
            float4 w1 = *(const float4*)&wp[kk * CH + 4];
            float wv[8] = {w0.x, w0.y, w0.z, w0.w, w1.x, w1.y, w1.z, w1.w};
#pragma unroll
            for (int c = 0; c < 8; c++) acc[0][c] += a0.x * wv[c];
#pragma unroll
            for (int c = 0; c < 8; c++) acc[1][c] += a0.y * wv[c];
        }
        k0 += ksize;
        __syncthreads();
    }

    // write out: lane rows {2l, 2l+1}, cols wcb..wcb+7
#pragma unroll
    for (int r = 0; r < 2; r++) {
        size_t row = rowbase + 2 * l + r;
        *(float4*)&y0[row * CH + wcb] =
            make_float4(acc[r][0], acc[r][1], acc[r][2], acc[r][3]);
        *(float4*)&y0[row * CH + wcb + 4] =
            make_float4(acc[r][4], acc[r][5], acc[r][6], acc[r][7]);
    }
}

// ---------------------------------------------------------------------------
// K3 helpers (gather/gemm/pool unchanged from r7)
// ---------------------------------------------------------------------------
__device__ __forceinline__ void gather_combine(
    const float* __restrict__ in, float* __restrict__ out,
    const int* __restrict__ rpl, const u16* __restrict__ ebg, float e,
    const float* __restrict__ b1, int t) {
    const int ch = t & 31;
    const int hw = t >> 5;   // 0..15
    for (int n = hw; n < ROI; n += 16) {
        int b = rpl[n], en = rpl[n + 1];
        float acc = 0.f;
        int j = b;
        for (; j + 3 < en; j += 4) {
            int p0 = ebg[j], p1 = ebg[j + 1], p2 = ebg[j + 2], p3 = ebg[j + 3];
            float v0 = in[p0 + ch], v1 = in[p1 + ch];
            float v2 = in[p2 + ch], v3 = in[p3 + ch];
            acc += (v0 + v1) + (v2 + v3);
        }
        for (; j < en; ++j) acc += in[ebg[j] + ch];
        out[n * SR + ch] = leakyf(e * in[n * SR + ch] + acc + b1[ch]);
    }
}

template <bool AFFINE>
__device__ __forceinline__ void gemm_inplace(float* __restrict__ buf,
                                             const float* __restrict__ w,
                                             const float* __restrict__ bias,
                                             const float* __restrict__ sc,
                                             const float* __restrict__ sh, int t) {
    for (int u = t; u < ROI * 2; u += 512) {
        const int r0 = (u >> 2) * 2;
        const int cq = u & 3;
        float acc0[8], acc1[8];
#pragma unroll
        for (int c = 0; c < 8; c++) {
            float b = AFFINE ? bias[cq * 8 + c] : 0.f;
            acc0[c] = b;
            acc1[c] = b;
        }
        const float* row0 = &buf[r0 * SR];
        const float* row1 = row0 + SR;
        // unroll 2 ONLY: full unroll -> >128 VGPR -> scratch spill (history)
#pragma unroll 2
        for (int k = 0; k < CH; k += 2) {
            float2 a0 = *(const float2*)&row0[k];
            float2 a1 = *(const float2*)&row1[k];
            const float* wr0 = &w[k * CH + cq * 8];
            const float* wr1 = wr0 + CH;
            float4 wa = *(const float4*)wr0;
            float4 wb = *(const float4*)(wr0 + 4);
            float4 wc = *(const float4*)wr1;
            float4 wd = *(const float4*)(wr1 + 4);
            acc0[0] += a0.x * wa.x + a0.y * wc.x;
            acc0[1] += a0.x * wa.y + a0.y * wc.y;
            acc0[2] += a0.x * wa.z + a0.y * wc.z;
            acc0[3] += a0.x * wa.w + a0.y * wc.w;
            acc0[4] += a0.x * wb.x + a0.y * wd.x;
            acc0[5] += a0.x * wb.y + a0.y * wd.y;
            acc0[6] += a0.x * wb.z + a0.y * wd.z;
            acc0[7] += a0.x * wb.w + a0.y * wd.w;
            acc1[0] += a1.x * wa.x + a1.y * wc.x;
            acc1[1] += a1.x * wa.y + a1.y * wc.y;
            acc1[2] += a1.x * wa.z + a1.y * wc.z;
            acc1[3] += a1.x * wa.w + a1.y * wc.w;
            acc1[4] += a1.x * wb.x + a1.y * wd.x;
            acc1[5] += a1.x * wb.y + a1.y * wd.y;
            acc1[6] += a1.x * wb.z + a1.y * wd.z;
            acc1[7] += a1.x * wb.w + a1.y * wd.w;
        }
        float* o0 = &buf[r0 * SR + cq * 8];
        float* o1 = o0 + SR;
#pragma unroll
        for (int c = 0; c < 8; c += 2) {
            float h00 = acc0[c], h01 = acc0[c + 1];
            float h10 = acc1[c], h11 = acc1[c + 1];
            if (AFFINE) {
                float s0 = sc[cq * 8 + c], t0 = sh[cq * 8 + c];
                float s1 = sc[cq * 8 + c + 1], t1 = sh[cq * 8 + c + 1];
                h00 = leakyf(h00 * s0 + t0);
                h01 = leakyf(h01 * s1 + t1);
                h10 = leakyf(h10 * s0 + t0);
                h11 = leakyf(h11 * s1 + t1);
            }
            *(float2*)&o0[c] = make_float2(h00, h01);
            *(float2*)&o1[c] = make_float2(h10, h11);
        }
    }
}

__device__ __forceinline__ void pool_store(const float* __restrict__ h,
                                           float* __restrict__ psc, int t) {
    const int ch = t & 31;
    const int hw = t >> 5;
    const int wave = t >> 6;
    float s = 0.f, m = -1e30f;
    for (int n = hw; n < ROI; n += 16) {
        float v = h[n * SR + ch];
        s += v;
        m = fmaxf(m, v);
    }
    s += __shfl_down(s, 32);
    m = fmaxf(m, __shfl_down(m, 32));
    if ((t & 63) < 32) {
        psc[wave * 32 + ch] = s;
        psc[256 + wave * 32 + ch] = m;
    }
}

__device__ __forceinline__ void pool_final(const float* __restrict__ psc,
                                           float* __restrict__ zg, int t) {
    if (t < 32) {
        float s = 0.f, m = -1e30f;
#pragma unroll
        for (int wv = 0; wv < 8; wv++) {
            s += psc[wv * 32 + t];
            m = fmaxf(m, psc[256 + wv * 32 + t]);
        }
        zg[t] = m;
        zg[CH + t] = s / (float)ROI;
    }
}

// ---------------------------------------------------------------------------
// K3: fused GIN layers + poolings + HEAD MLP (v8: k_head absorbed).
// z stays in LDS (zloc[128]); head's 3 GEMMs run in-block at the tail:
// h1 (256) reuses psc after the last pool_final; h2 reuses zloc after h1
// consumed it. Head weights (~262KB/block) are L2-resident across blocks.
// Removes one dispatch + launch gap + the z global round-trip.
// LDS ~79.5KB -> still 2 blocks/CU.
// ---------------------------------------------------------------------------
__global__ __launch_bounds__(512, 2) void k_gin(
    const float* __restrict__ y0, const int* __restrict__ gcnt,
    const u32* __restrict__ pairs, u16* __restrict__ ebuf,
    const float* __restrict__ eps0p,
    const float* __restrict__ b1_0, const float* __restrict__ W2_0,
    const float* __restrict__ b2_0, const float* __restrict__ bn0_g,
    const float* __restrict__ bn0_b, const float* __restrict__ bn0_m,
    const float* __restrict__ bn0_v, const float* __restrict__ eps1p,
    const float* __restrict__ W1_1, const float* __restrict__ b1_1,
    const float* __restrict__ W2_1, const float* __restrict__ b2_1,
    const float* __restrict__ bn1_g, const float* __restrict__ bn1_b,
    const float* __restrict__ bn1_m, const float* __restrict__ bn1_v,
    const float* __restrict__ hW1, const float* __restrict__ hb1,
    const float* __restrict__ hg1, const float* __restrict__ hbe1,
    const float* __restrict__ hm1, const float* __restrict__ hv1,
    const float* __restrict__ hW2, const float* __restrict__ hb2,
    const float* __restrict__ hg2, const float* __restrict__ hbe2,
    const float* __restrict__ hm2, const float* __restrict__ hv2,
    const float* __restrict__ hW3, const float* __restrict__ hb3,
    float* __restrict__ out) {
    __shared__ float bufA[ROI * SR];     // 35376 B
    __shared__ float bufB[ROI * SR];     // 35376 B
    __shared__ float w[CH * CH];         // 4096 B
    __shared__ int rpl[RPS];             // 1076 B: hist -> exclusive bases
    __shared__ float prm[8 * CH];        // 1024 B
    __shared__ float psc[512];           // 2048 B: scan | cursors | pool | h1
    __shared__ float zloc[128];          // 512 B: pooled features -> h2
    __shared__ float epss[2];

    const int t = threadIdx.x;
    const int g = blockIdx.x;
    const u32* pg = pairs + (size_t)g * CAP;
    u16* ebg = ebuf + (size_t)g * CAP;
    const int cnt = (gcnt[g] < CAP) ? gcnt[g] : CAP;

    if (t < CH) {
        prm[0 * CH + t] = b1_0[t];
        prm[1 * CH + t] = b2_0[t];
        float s0 = bn0_g[t] * rsqrtf(bn0_v[t] + BN_EPS);
        prm[2 * CH + t] = s0;
        prm[3 * CH + t] = bn0_b[t] - bn0_m[t] * s0;
        prm[4 * CH + t] = b1_1[t];
        prm[5 * CH + t] = b2_1[t];
        float s1 = bn1_g[t] * rsqrtf(bn1_v[t] + BN_EPS);
        prm[6 * CH + t] = s1;
        prm[7 * CH + t] = bn1_b[t] - bn1_m[t] * s1;
    }
    if (t == 0) {
        epss[0] = 1.0f + *eps0p;
        epss[1] = 1.0f + *eps1p;
    }
    if (t < RPS) rpl[t] = 0;

    // stage y0 tile
    const float* yg = y0 + (size_t)g * ROI * CH;
    for (int f = t; f < (ROI * CH) / 4; f += 512) {
        float4 v = ((const float4*)yg)[f];
        int row = f >> 3, c4 = (f & 7) << 2;
        float* p = &bufA[row * SR + c4];
        *(float2*)p = make_float2(v.x, v.y);
        *(float2*)(p + 2) = make_float2(v.z, v.w);
    }
    for (int i = t; i < (CH * CH) / 4; i += 512)
        ((float4*)w)[i] = ((const float4*)W2_0)[i];
    __syncthreads();

    // ---- in-LDS CSR build ----
    for (int i = t; i < cnt; i += 512) atomicAdd(&rpl[pg[i] >> 16], 1);
    __syncthreads();
    int* s = (int*)psc;
    int v = (t < ROI) ? rpl[t] : 0;
    s[t] = v;
    __syncthreads();
    for (int d = 1; d < 512; d <<= 1) {
        int u = (t >= d) ? s[t - d] : 0;
        __syncthreads();
        s[t] += u;
        __syncthreads();
    }
    int inc = s[t];
    if (t < ROI) rpl[t] = inc - v;       // exclusive base
    if (t == 511) rpl[ROI] = inc;        // total
    __syncthreads();
    int* cur = (int*)psc;
    if (t < ROI) cur[t] = rpl[t];
    __syncthreads();
    for (int i = t; i < cnt; i += 512) {
        u32 p = pg[i];
        int pos = atomicAdd(&cur[p >> 16], 1);
        ebg[pos] = (u16)(p & 0xffffu);
    }
    __syncthreads();

    // ---- layer 0 ----
    gather_combine(bufA, bufB, rpl, ebg, epss[0], &prm[0 * CH], t);
    __syncthreads();

    gemm_inplace<true>(bufB, w, &prm[1 * CH], &prm[2 * CH], &prm[3 * CH], t);
    __syncthreads();

    pool_store(bufB, psc, t);
    for (int i = t; i < (CH * CH) / 4; i += 512)
        ((float4*)w)[i] = ((const float4*)W1_1)[i];
    __syncthreads();

    pool_final(psc, zloc, t);
    gemm_inplace<false>(bufB, w, nullptr, nullptr, nullptr, t);
    __syncthreads();

    // ---- layer 1 ----
    gather_combine(bufB, bufA, rpl, ebg, epss[1], &prm[4 * CH], t);
    for (int i = t; i < (CH * CH) / 4; i += 512)
        ((float4*)w)[i] = ((const float4*)W2_1)[i];
    __syncthreads();

    gemm_inplace<true>(bufA, w, &prm[5 * CH], &prm[6 * CH], &prm[7 * CH], t);
    __syncthreads();

    pool_store(bufA, psc, t);
    __syncthreads();
    pool_final(psc, zloc + 64, t);
    __syncthreads();

    // ---- head MLP: zloc[128] -> 256 -> 128 -> 1 ----
    float* h1 = psc;   // psc free after pool_final consumed it
    if (t < 256) {
        float a = hb1[t];
#pragma unroll 8
        for (int k = 0; k < 128; k++) a += zloc[k] * hW1[k * 256 + t];
        float sc = hg1[t] * rsqrtf(hv1[t] + BN_EPS);
        a = (a - hm1[t]) * sc + hbe1[t];
        h1[t] = leakyf(a);
    }
    __syncthreads();
    if (t < 128) {
        float a = hb2[t];
#pragma unroll 8
        for (int k = 0; k < 256; k++) a += h1[k] * hW2[k * 128 + t];
        float sc = hg2[t] * rsqrtf(hv2[t] + BN_EPS);
        a = (a - hm2[t]) * sc + hbe2[t];
        zloc[t] = leakyf(a);   // zloc free after h1 consumed it
    }
    __syncthreads();
    if (t < 64) {
        float vv = zloc[t] * hW3[t] + zloc[t + 64] * hW3[t + 64];
        for (int offd = 32; offd; offd >>= 1) vv += __shfl_down(vv, offd);
        if (t == 0) out[g] = vv + hb3[0];
    }
}

// ---------------------------------------------------------------------------
extern "C" void kernel_launch(void* const* d_in, const int* in_sizes, int n_in,
                              void* d_out, int out_size, void* d_ws, size_t ws_size,
                              hipStream_t stream) {
    const float* x      = (const float*)d_in[0];
    const int* eidx     = (const int*)d_in[1];
    const float* eps0   = (const float*)d_in[3];
    const float* W1_0   = (const float*)d_in[4];
    const float* b1_0   = (const float*)d_in[5];
    const float* W2_0   = (const float*)d_in[6];
    const float* b2_0   = (const float*)d_in[7];
    const float* bn0_g  = (const float*)d_in[8];
    const float* bn0_b  = (const float*)d_in[9];
    const float* bn0_m  = (const float*)d_in[10];
    const float* bn0_v  = (const float*)d_in[11];
    const float* eps1   = (const float*)d_in[12];
    const float* W1_1   = (const float*)d_in[13];
    const float* b1_1   = (const float*)d_in[14];
    const float* W2_1   = (const float*)d_in[15];
    const float* b2_1   = (const float*)d_in[16];
    const float* bn1_g  = (const float*)d_in[17];
    const float* bn1_b  = (const float*)d_in[18];
    const float* bn1_m  = (const float*)d_in[19];
    const float* bn1_v  = (const float*)d_in[20];
    const float* lin1_W = (const float*)d_in[21];
    const float* lin1_b = (const float*)d_in[22];
    const float* hbn1_g = (const float*)d_in[23];
    const float* hbn1_b = (const float*)d_in[24];
    const float* hbn1_m = (const float*)d_in[25];
    const float* hbn1_v = (const float*)d_in[26];
    const float* lin2_W = (const float*)d_in[27];
    const float* lin2_b = (const float*)d_in[28];
    const float* hbn2_g = (const float*)d_in[29];
    const float* hbn2_b = (const float*)d_in[30];
    const float* hbn2_m = (const float*)d_in[31];
    const float* hbn2_v = (const float*)d_in[32];
    const float* lin3_W = (const float*)d_in[33];
    const float* lin3_b = (const float*)d_in[34];

    const int E = in_sizes[1] / 2;
    const int* src = eidx;
    const int* dst = eidx + E;

    char* ws = (char*)d_ws;
    const size_t Y0_OFF = 0;
    const size_t GC_OFF = (size_t)NNODES * CH * 4;           // 17,563,648
    const size_t PR_OFF = GC_OFF + 2048;
    const size_t EB_OFF = PR_OFF + (size_t)NG * CAP * 4;     // pairs 5.24MB

    float* y0  = (float*)(ws + Y0_OFF);
    int* gcnt  = (int*)(ws + GC_OFF);
    u32* pairs = (u32*)(ws + PR_OFF);
    u16* ebuf  = (u16*)(ws + EB_OFF);

    hipMemsetAsync(gcnt, 0, 2048, stream);
    k_gemmbkt<<<NB_G1 + NB_BKT, 256, 0, stream>>>(x, W1_0, y0, src, dst, E,
                                                  gcnt, pairs);

    k_gin<<<NG, 512, 0, stream>>>(y0, gcnt, pairs, ebuf, eps0, b1_0, W2_0,
                                  b2_0, bn0_g, bn0_b, bn0_m, bn0_v, eps1,
                                  W1_1, b1_1, W2_1, b2_1, bn1_g, bn1_b,
                                  bn1_m, bn1_v,
                                  lin1_W, lin1_b, hbn1_g, hbn1_b, hbn1_m,
                                  hbn1_v, lin2_W, lin2_b, hbn2_g, hbn2_b,
                                  hbn2_m, hbn2_v, lin3_W, lin3_b,
                                  (float*)d_out);
}